// Round 2
// baseline (655.429 us; speedup 1.0000x reference)
//
#include <hip/hip_runtime.h>
#include <math.h>

#define HW 4096

typedef __attribute__((ext_vector_type(8))) short bh8;
typedef __attribute__((ext_vector_type(4))) float f32x4;
typedef __attribute__((ext_vector_type(2))) unsigned int u32x2;
typedef unsigned int u32;
typedef unsigned short u16;

__device__ __forceinline__ u16 f2bf(float f) {
  union { float f; u32 u; } v; v.f = f;
  u32 u = v.u;
  return (u16)((u + 0x7FFFu + ((u >> 16) & 1u)) >> 16);
}
__device__ __forceinline__ float bf2f(u16 h) {
  union { u32 u; float f; } v; v.u = ((u32)h) << 16;
  return v.f;
}
__device__ __forceinline__ u32 cvt_pk_bf16(float lo, float hi) {
  u32 r;
  asm("v_cvt_pk_bf16_f32 %0, %1, %2" : "=v"(r) : "v"(lo), "v"(hi));
  return r;
}
__device__ __forceinline__ float fexp2(float x) {
  float r;
  asm("v_exp_f32 %0, %1" : "=v"(r) : "v"(x));
  return r;
}

// ---------------------------------------------------------------------------
// kv projection (+ fused conv-weight convert prologue).  (unchanged)
// ---------------------------------------------------------------------------
__global__ __launch_bounds__(256) void kv_proj(
    const float* __restrict__ xs,
    const float* __restrict__ w1, const float* __restrict__ b1,
    const float* __restrict__ w2, const float* __restrict__ b2,
    u32* __restrict__ Knm, u16* __restrict__ Vcm,
    u16* __restrict__ K2t, u16* __restrict__ V2t,
    const float* __restrict__ cw, const float* __restrict__ gamma,
    const float* __restrict__ beta, const float* __restrict__ mean,
    const float* __restrict__ var, u16* __restrict__ Wg,
    float* __restrict__ shb) {
  __shared__ float Ss[64][65];
  __shared__ float Ws[128 * 64];
  __shared__ u32 LtK[64][33];  // packed bf16x2 K rows, conflict-free pitch
  const int b = blockIdx.y, n0 = blockIdx.x * 64;
  const int t = threadIdx.x;
  const int lane_n = t & 63, jg = t >> 6;
  const int jbase = jg * 32;
  const float* xsb = xs + (size_t)b * 128 * HW;

  // ---- fused wcvt: conv_w (oc,ic,3,3) -> Wg[tap][oc][ic] bf16, BN folded ----
  {
    int gid = (blockIdx.y * 64 + blockIdx.x) * 256 + t;  // 0..131071
    for (int i = gid; i < 147456; i += 131072) {
      int tap = i >> 14, oc = (i >> 7) & 127, ic = i & 127;
      float sc = gamma[oc] * rsqrtf(var[oc] + 1e-5f);
      Wg[i] = f2bf(cw[((size_t)(oc * 128 + ic)) * 9 + tap] * sc);
    }
    if (gid < 128) {
      float sc = gamma[gid] * rsqrtf(var[gid] + 1e-5f);
      shb[gid] = beta[gid] - mean[gid] * sc;
    }
  }

  for (int br = 0; br < 2; ++br) {
    const float* W = br ? w2 : w1;
    const float* bias = br ? b2 : b1;
    const float* src = xsb + (br ? 64 * HW : 0);
    __syncthreads();
    for (int s = 0; s < 16; ++s) {
      int ch = s * 4 + jg;
      Ss[ch][lane_n] = src[(size_t)ch * HW + n0 + lane_n];
    }
    for (int i = t; i < 128 * 64; i += 256) Ws[i] = W[i];
    __syncthreads();

    float acc[32];
#pragma unroll
    for (int i = 0; i < 32; ++i) acc[i] = bias[jbase + i];
    for (int ch = 0; ch < 64; ++ch) {
      float s = Ss[ch][lane_n];
#pragma unroll
      for (int i = 0; i < 32; ++i) acc[i] = fmaf(Ws[(jbase + i) * 64 + ch], s, acc[i]);
    }

    if (br == 0) {
      if (jg < 2) {  // K channels jbase..jbase+31 -> pack to LDS
#pragma unroll
        for (int i2 = 0; i2 < 16; ++i2) {
          u32 p = (u32)f2bf(acc[2 * i2]) | ((u32)f2bf(acc[2 * i2 + 1]) << 16);
          LtK[lane_n][jg * 16 + i2] = p;
        }
      } else {  // V channels (jbase-64)..+31 -> bf16 ch-major global
#pragma unroll
        for (int i = 0; i < 32; ++i) {
          int ch = jbase - 64 + i;
          Vcm[((size_t)b * 64 + ch) * HW + n0 + lane_n] = f2bf(acc[i]);
        }
      }
      __syncthreads();
      // coalesced n-major K write: rows of 32 uints (64 bf16)
#pragma unroll
      for (int p = 0; p < 8; ++p) {
        int idx = p * 256 + t;
        int n = idx >> 5, cc = idx & 31;
        Knm[((size_t)b * HW + n0 + n) * 32 + cc] = LtK[n][cc];
      }
    } else {  // channel branch: bf16 ch-major K2t/V2t
      u16* Kt = K2t + (size_t)b * 64 * HW;
      u16* Vt = V2t + (size_t)b * 64 * HW;
#pragma unroll
      for (int i = 0; i < 32; ++i) {
        int j = jbase + i;
        u16* dst = (j < 64) ? (Kt + (size_t)j * HW) : (Vt + (size_t)(j - 64) * HW);
        dst[n0 + lane_n] = f2bf(acc[i]);
      }
    }
  }
}

// ---------------------------------------------------------------------------
// Fused dispatch, r8: 512-thread blocks. Blocks x<64 run MFMA flash attention
// with 8 key-slicing waves over 256-key tiles (2x the wave-parallelism of r7
// at identical per-step code and identical K/V traffic); blocks x>=64 run
// chan_gram partials (16 blocks/batch x 256 n). P stays in registers
// (cvt_pk_bf16 + permlane32/16_swap); softmax offset dropped entirely (scale
// cancels in O/lsum normalization). __launch_bounds__(512,4) caps VGPR at 128
// -> 2 blocks/CU = 16 waves/CU resident.
// grid (80, 8 b), block 512
// ---------------------------------------------------------------------------
__device__ __forceinline__ void attn_step(
    const bh8* kf, const bh8* vf, const bh8 (&qb)[4][2], const bh8 ones,
    f32x4 (&O)[4][4], f32x4 (&Osum)[4]) {
  f32x4 S[2][4];
  __builtin_amdgcn_s_setprio(1);
#pragma unroll
  for (int mt = 0; mt < 2; ++mt)
#pragma unroll
    for (int nt = 0; nt < 4; ++nt) {
      f32x4 a = (f32x4)(0.f);
      a = __builtin_amdgcn_mfma_f32_16x16x32_bf16(kf[mt * 2 + 0], qb[nt][0], a, 0, 0, 0);
      a = __builtin_amdgcn_mfma_f32_16x16x32_bf16(kf[mt * 2 + 1], qb[nt][1], a, 0, 0, 0);
      S[mt][nt] = a;
    }
  __builtin_amdgcn_s_setprio(0);
#pragma unroll
  for (int nt = 0; nt < 4; ++nt) {
    // p = exp2(S)  (Q prescaled by log2e; global scale cancels at normalize)
    float e00 = fexp2(S[0][nt][0]), e01 = fexp2(S[0][nt][1]);
    float e02 = fexp2(S[0][nt][2]), e03 = fexp2(S[0][nt][3]);
    float e10 = fexp2(S[1][nt][0]), e11 = fexp2(S[1][nt][1]);
    float e12 = fexp2(S[1][nt][2]), e13 = fexp2(S[1][nt][3]);
    u32 A = cvt_pk_bf16(e00, e01);  // m0, keys quad*4+{0,1}
    u32 B = cvt_pk_bf16(e02, e03);  // m0, keys quad*4+{2,3}
    u32 C = cvt_pk_bf16(e10, e11);  // m1, keys 16+quad*4+{0,1}
    u32 D = cvt_pk_bf16(e12, e13);  // m1, keys 16+quad*4+{2,3}
    // redistribute (q=lane&15 preserved):
    // consumer quad qc needs m=qc>>1 from producer quads (qc&1)*2, (qc&1)*2+1
    u32x2 rac = __builtin_amdgcn_permlane32_swap(A, C, 0, 0);
    u32x2 rbd = __builtin_amdgcn_permlane32_swap(B, D, 0, 0);
    u32x2 r02 = __builtin_amdgcn_permlane16_swap(rac.x, rac.y, 0, 0);
    u32x2 r13 = __builtin_amdgcn_permlane16_swap(rbd.x, rbd.y, 0, 0);
    union { u32 u[4]; bh8 v; } pb;
    pb.u[0] = r02.x;  // keys quad*8+{0,1}
    pb.u[1] = r13.x;  // keys quad*8+{2,3}
    pb.u[2] = r02.y;  // keys quad*8+{4,5}
    pb.u[3] = r13.y;  // keys quad*8+{6,7}
    __builtin_amdgcn_s_setprio(1);
#pragma unroll
    for (int ct = 0; ct < 4; ++ct)
      O[ct][nt] = __builtin_amdgcn_mfma_f32_16x16x32_bf16(vf[ct], pb.v, O[ct][nt], 0, 0, 0);
    Osum[nt] = __builtin_amdgcn_mfma_f32_16x16x32_bf16(ones, pb.v, Osum[nt], 0, 0, 0);
    __builtin_amdgcn_s_setprio(0);
  }
}

#define LOADKV(KB, KF, VF)                                            \
  do {                                                                \
    const int n0_ = (KB) * 256;                                       \
    const u16* kr_ = Kb + (size_t)(n0_ + wb + lq) * 64 + quad * 8;    \
    KF[0] = *(const bh8*)(kr_);                                       \
    KF[1] = *(const bh8*)(kr_ + 32);                                  \
    KF[2] = *(const bh8*)(kr_ + 1024);                                \
    KF[3] = *(const bh8*)(kr_ + 1056);                                \
    const u16* vr_ = Vb + (size_t)lq * HW + n0_ + wb + quad * 8;      \
    VF[0] = *(const bh8*)(vr_);                                       \
    VF[1] = *(const bh8*)(vr_ + 16 * HW);                             \
    VF[2] = *(const bh8*)(vr_ + 32 * HW);                             \
    VF[3] = *(const bh8*)(vr_ + 48 * HW);                             \
  } while (0)

__global__ __launch_bounds__(512, 4) void attn_gram(
    const float* __restrict__ xu, const float* __restrict__ xs,
    const u16* __restrict__ Knm, const u16* __restrict__ Vcm,
    u16* __restrict__ xcat,
    const u16* __restrict__ K2t, float* __restrict__ Mp) {
  __shared__ __align__(16) u16 SMEM[18432];  // 36864 B (attn epi) / 33280 B (gram)
  const int b = blockIdx.y;
  const int t = threadIdx.x;

  if (blockIdx.x >= 64) {
    // ---------------- chan_gram path: 256 n per block, 512 thr ----------------
    float* Us = (float*)SMEM;      // [64][65]
    float* Ksm = Us + 64 * 65;     // [64][65]  -> 33280 B total
    const int n0 = (blockIdx.x - 64) * 256;
    const int c = t & 63, dg = t >> 6;  // dg 0..7
    const float* ub = xu + ((size_t)b * 128 + 64) * HW;
    const u16* kb2 = K2t + (size_t)b * 64 * HW;
    float acc[8];
#pragma unroll
    for (int i = 0; i < 8; ++i) acc[i] = 0.f;
    for (int s = 0; s < 4; ++s) {
      int nn = n0 + s * 64;
      __syncthreads();
      for (int r = 0; r < 8; ++r) {
        int row = r * 8 + dg;
        Us[row * 65 + c] = ub[(size_t)row * HW + nn + c];
        Ksm[row * 65 + c] = bf2f(kb2[(size_t)row * HW + nn + c]);
      }
      __syncthreads();
      for (int n = 0; n < 64; ++n) {
        float u = Us[c * 65 + n];
#pragma unroll
        for (int i = 0; i < 8; ++i)
          acc[i] = fmaf(Ksm[(dg * 8 + i) * 65 + n], u, acc[i]);
      }
    }
    float* dst = Mp + ((size_t)(blockIdx.x - 64) * 8 + b) * 4096 + c * 64 + dg * 8;
#pragma unroll
    for (int i = 0; i < 8; ++i) dst[i] = acc[i];
    return;
  }

  // ---------------- attention path: 8 key-slicing waves ----------------
  const int q0 = blockIdx.x * 64;
  const int wq = t >> 6, lane = t & 63, lq = lane & 15, quad = lane >> 4;
  const int wb = wq * 32;  // wave's key-slice base within a 256-key tile
  const float* xub = xu + (size_t)b * 128 * HW;
  const float* xsb = xs + (size_t)b * 128 * HW;
  const u16* Kb = Knm + (size_t)b * HW * 64;
  const u16* Vb = Vcm + (size_t)b * 64 * HW;

  // Q B-fragments: all 64 q x 64 ch per wave, prescaled by log2(e)
  bh8 qb[4][2];
#pragma unroll
  for (int nt = 0; nt < 4; ++nt)
#pragma unroll
    for (int s = 0; s < 2; ++s)
#pragma unroll
      for (int j = 0; j < 8; ++j) {
        int ch = s * 32 + quad * 8 + j;
        qb[nt][s][j] =
            (short)f2bf(xub[(size_t)ch * HW + q0 + nt * 16 + lq] * 1.44269504f);
      }
  bh8 ones;
#pragma unroll
  for (int j = 0; j < 8; ++j) ones[j] = (short)0x3F80;  // bf16 1.0

  f32x4 O[4][4];  // [ct: ch-tile][nt: q-tile], C: row=ch_local, col=q_local
#pragma unroll
  for (int ct = 0; ct < 4; ++ct)
#pragma unroll
    for (int nt = 0; nt < 4; ++nt) O[ct][nt] = (f32x4)(0.f);
  f32x4 Osum[4];  // all rows identical = sum over wave's keys, per q
#pragma unroll
  for (int nt = 0; nt < 4; ++nt) Osum[nt] = (f32x4)(0.f);

  bh8 kfa[4], vfa[4], kfb[4], vfb[4];
  LOADKV(0, kfa, vfa);
  for (int kb = 0; kb < 16; kb += 2) {
    LOADKV(kb + 1, kfb, vfb);
    attn_step(kfa, vfa, qb, ones, O, Osum);
    if (kb + 2 < 16) LOADKV(kb + 2, kfa, vfa);
    attn_step(kfb, vfb, qb, ones, O, Osum);
  }

  // ---- epilogue: cross-8-wave reduce, normalize, shortcut, bf16 store ----
  // 4 rounds of 16 ch; Posc [8 waves][16 ch][68 q] = 34816 B, Lred 2048 B
  float* Posc = (float*)SMEM;
  float* Lred = (float*)(SMEM + 17408);
  if (quad == 0) {
#pragma unroll
    for (int nt = 0; nt < 4; ++nt) Lred[(wq * 4 + nt) * 16 + lq] = Osum[nt][0];
  }

  const int q = t >> 3, cs = t & 7;  // reader mapping: 64 q x 8 ch-groups
  float inv = 0.f;
#pragma unroll
  for (int ct = 0; ct < 4; ++ct) {
    if (ct) __syncthreads();  // previous round's readers done
#pragma unroll
    for (int nt = 0; nt < 4; ++nt)
#pragma unroll
      for (int r = 0; r < 4; ++r)
        Posc[(wq * 16 + quad * 4 + r) * 68 + nt * 16 + lq] = O[ct][nt][r];
    __syncthreads();
    if (ct == 0) {
      float li = 0.f;
#pragma unroll
      for (int w2 = 0; w2 < 8; ++w2) li += Lred[w2 * 64 + q];
      inv = 1.f / li;
    }
    u16 h[2];
#pragma unroll
    for (int i = 0; i < 2; ++i) {
      int chl = cs * 2 + i;
      float s = 0.f;
#pragma unroll
      for (int w2 = 0; w2 < 8; ++w2) s += Posc[(w2 * 16 + chl) * 68 + q];
      int ch = ct * 16 + chl;
      size_t g = (size_t)ch * HW + q0 + q;
      h[i] = f2bf(s * inv + xub[g] + xsb[g]);
    }
    u32 pk = (u32)h[0] | ((u32)h[1] << 16);
    *(u32*)(xcat + ((size_t)b * HW + q0 + q) * 128 + ct * 16 + cs * 2) = pk;
  }
}

// reduce 16 chunk-partials -> M. grid 128, block 256.
__global__ void chan_reduce(const float* __restrict__ Mp, float* __restrict__ M) {
  int idx = blockIdx.x * 256 + threadIdx.x;  // 32768 cells
  float s = 0.f;
  for (int ch = 0; ch < 16; ++ch) s += Mp[(size_t)ch * 32768 + idx];
  M[idx] = s;
}

// ---------------------------------------------------------------------------
// chan_apply with fused softmax (unchanged)
// ---------------------------------------------------------------------------
__global__ __launch_bounds__(256) void chan_apply(
    const u16* __restrict__ V2t, const float* __restrict__ M,
    const float* __restrict__ xu, const float* __restrict__ xs,
    u16* __restrict__ xcat) {
  __shared__ float Vsm[64][65];
  __shared__ float As[64][65];
  __shared__ float red1[4][64], red2[4][64];
  const int b = blockIdx.y, n0 = blockIdx.x * 64, t = threadIdx.x;
  const int lane = t & 63, dg = t >> 6;
  const u16* Vb = V2t + (size_t)b * 64 * HW;
  for (int s = 0; s < 16; ++s) {
    int c = s * 4 + dg;
    Vsm[lane][c] = bf2f(Vb[(size_t)c * HW + n0 + lane]);
  }
  for (int idx = t; idx < 4096; idx += 256) As[idx >> 6][idx & 63] = M[b * 4096 + idx];
  __syncthreads();
  // softmax over c per d=lane; this thread owns c in [dg*16, dg*16+16)
  float mx = -1e30f;
#pragma unroll
  for (int i = 0; i < 16; ++i) mx = fmaxf(mx, As[dg * 16 + i][lane]);
  red1[dg][lane] = mx;
  __syncthreads();
  mx = fmaxf(fmaxf(red1[0][lane], red1[1][lane]), fmaxf(red1[2][lane], red1[3][lane]));
  float se = 0.f;
#pragma unroll
  for (int i = 0; i < 16; ++i) {
    float e = __expf(As[dg * 16 + i][lane] - mx);
    As[dg * 16 + i][lane] = e;  // own cells only
    se += e;
  }
  red2[dg][lane] = se;
  __syncthreads();

  float acc[16];
#pragma unroll
  for (int i = 0; i < 16; ++i) acc[i] = 0.f;
  for (int c = 0; c < 64; ++c) {
    float v = Vsm[lane][c];
#pragma unroll
    for (int i = 0; i < 16; ++i) acc[i] = fmaf(v, As[c][dg * 16 + i], acc[i]);
  }
  const float* xub = xu + ((size_t)b * 128 + 64) * HW;
  const float* xsb = xs + ((size_t)b * 128 + 64) * HW;
  const int n = n0 + lane;
  u16 hv[16];
#pragma unroll
  for (int i = 0; i < 16; ++i) {
    int d = dg * 16 + i;
    float sm = red2[0][d] + red2[1][d] + red2[2][d] + red2[3][d];
    hv[i] = f2bf(acc[i] / sm + xub[(size_t)d * HW + n] + xsb[(size_t)d * HW + n]);
  }
  u32 pk[8];
#pragma unroll
  for (int j = 0; j < 8; ++j) pk[j] = (u32)hv[2 * j] | ((u32)hv[2 * j + 1] << 16);
  u16* ob = xcat + ((size_t)b * HW + n) * 128 + 64 + dg * 16;
  *(uint4*)(ob) = make_uint4(pk[0], pk[1], pk[2], pk[3]);
  *(uint4*)(ob + 8) = make_uint4(pk[4], pk[5], pk[6], pk[7]);
}

// ---------------------------------------------------------------------------
// Implicit-GEMM 3x3 conv via bf16 MFMA + fused BN(folded) + ReLU. (unchanged)
// ---------------------------------------------------------------------------
__global__ __launch_bounds__(512) void conv_mfma(
    const u16* __restrict__ X, const u16* __restrict__ Wg,
    const float* __restrict__ shb, float* __restrict__ out) {
  __shared__ __align__(16) u16 In[4 * 66 * 136];
  __shared__ __align__(16) u16 Wt[2][128 * 136];
  const int b = blockIdx.y, h0 = blockIdx.x * 2;
  const int t = threadIdx.x;
  const int wq = t >> 6, lane = t & 63, lq = lane & 15, quad = lane >> 4;
  const int nb = (wq & 1) * 64;       // oc-half base
  const int mb = (wq >> 1) * 2;       // m-tile pair base
  const u16* Xb = X + (size_t)b * HW * 128;

  // zero w-halo cells (iw = 0 and 65 for each ih)
  if (t < 128) {
    int ih = t >> 5, iwsel = (t >> 4) & 1, ck = t & 15;
    int iw = iwsel ? 65 : 0;
    *(uint4*)&In[(ih * 66 + iw) * 136 + ck * 8] = make_uint4(0, 0, 0, 0);
  }
  // stage input rows (zero h-halo out of range); 512 threads
  for (int ih = 0; ih < 4; ++ih) {
    int h = h0 - 1 + ih;
    bool ok = (h >= 0 && h < 64);
    const u16* src = Xb + (size_t)h * 64 * 128;
#pragma unroll
    for (int p = 0; p < 2; ++p) {
      int idx = p * 512 + t;
      int row = idx >> 4, ck = idx & 15;
      uint4 d = make_uint4(0, 0, 0, 0);
      if (ok) d = *(const uint4*)(src + (size_t)row * 128 + ck * 8);
      *(uint4*)&In[(ih * 66 + 1 + row) * 136 + ck * 8] = d;
    }
  }
  // stage tap-0 weights into buffer 0 (2048 uint4 over 512 threads = 4 passes)
  {
    const u16* src = Wg;
#pragma unroll
    for (int p = 0; p < 4; ++p) {
      int idx = p * 512 + t;
      int oc = idx >> 4, ck = idx & 15;
      uint4 d = *(const uint4*)(src + oc * 128 + ck * 8);
      *(uint4*)&Wt[0][oc * 136 + ck * 8] = d;
    }
  }
  __syncthreads();

  f32x4 acc[2][4];
#pragma unroll
  for (int mt = 0; mt < 2; ++mt)
#pragma unroll
    for (int nt = 0; nt < 4; ++nt) acc[mt][nt] = (f32x4)(0.f);

  for (int tap = 0; tap < 9; ++tap) {
    const int cur = tap & 1;
    if (tap < 8) {  // prefetch next tap into the other buffer
      const u16* src = Wg + (size_t)(tap + 1) * 128 * 128;
#pragma unroll
      for (int p = 0; p < 4; ++p) {
        int idx = p * 512 + t;
        int oc = idx >> 4, ck = idx & 15;
        uint4 d = *(const uint4*)(src + oc * 128 + ck * 8);
        *(uint4*)&Wt[cur ^ 1][oc * 136 + ck * 8] = d;
      }
    }
    const int dh = tap / 3, dw = tap - 3 * dh;
    const u16* Wc = &Wt[cur][0];
#pragma unroll
    for (int c = 0; c < 4; ++c) {
      bh8 bf[4];
#pragma unroll
      for (int nt = 0; nt < 4; ++nt)
        bf[nt] = *(const bh8*)&Wc[(nb + nt * 16 + lq) * 136 + c * 32 + quad * 8];
#pragma unroll
      for (int mt = 0; mt < 2; ++mt) {
        int s = (mb + mt) * 16 + lq;
        int ih = (s >> 6) + dh, iw = (s & 63) + dw;
        bh8 af = *(const bh8*)&In[(ih * 66 + iw) * 136 + c * 32 + quad * 8];
#pragma unroll
        for (int nt = 0; nt < 4; ++nt)
          acc[mt][nt] = __builtin_amdgcn_mfma_f32_16x16x32_bf16(af, bf[nt], acc[mt][nt], 0, 0, 0);
      }
    }
    __syncthreads();
  }

  // epilogue: +bias, ReLU, dense float4 stores
  float shv[4];
#pragma unroll
  for (int nt = 0; nt < 4; ++nt) shv[nt] = shb[nb + nt * 16 + lq];
#pragma unroll
  for (int mt = 0; mt < 2; ++mt) {
    int mtile = mb + mt;
    int h = h0 + (mtile >> 2);
    int w0 = ((mtile & 3) * 16) + quad * 4;
#pragma unroll
    for (int nt = 0; nt < 4; ++nt) {
      int oc = nb + nt * 16 + lq;
      float4 v;
      v.x = fmaxf(acc[mt][nt][0] + shv[nt], 0.f);
      v.y = fmaxf(acc[mt][nt][1] + shv[nt], 0.f);
      v.z = fmaxf(acc[mt][nt][2] + shv[nt], 0.f);
      v.w = fmaxf(acc[mt][nt][3] + shv[nt], 0.f);
      *(float4*)&out[((size_t)b * 128 + oc) * HW + h * 64 + w0] = v;
    }
  }
}

// ---------------------------------------------------------------------------
extern "C" void kernel_launch(void* const* d_in, const int* in_sizes, int n_in,
                              void* d_out, int out_size, void* d_ws, size_t ws_size,
                              hipStream_t stream) {
  const float* x_up   = (const float*)d_in[0];
  const float* x_skip = (const float*)d_in[1];
  const float* kv1_w  = (const float*)d_in[2];
  const float* kv1_b  = (const float*)d_in[3];
  const float* kv2_w  = (const float*)d_in[4];
  const float* kv2_b  = (const float*)d_in[5];
  const float* conv_w = (const float*)d_in[6];
  const float* bn_g   = (const float*)d_in[7];
  const float* bn_b   = (const float*)d_in[8];
  const float* bn_m   = (const float*)d_in[9];
  const float* bn_v   = (const float*)d_in[10];
  float* out = (float*)d_out;

  char* ws = (char*)d_ws;
  const size_t XCATB_B = (size_t)8 * HW * 128 * 2;  // 8.39 MB bf16 n-major
  const size_t KV16_B  = (size_t)8 * 64 * HW * 2;   // 4.19 MB
  size_t off = 0;
  u16*   xcat = (u16*)(ws + off);   off += XCATB_B;
  u16*   K2t  = (u16*)(ws + off);   off += KV16_B;
  u16*   V2t  = (u16*)(ws + off);   off += KV16_B;
  u32*   Knm  = (u32*)(ws + off);   off += KV16_B;
  u16*   Vcm  = (u16*)(ws + off);   off += KV16_B;
  float* Mp   = (float*)(ws + off); off += (size_t)32 * 8 * 4096 * 4;
  float* M    = (float*)(ws + off); off += (size_t)8 * 4096 * 4;
  u16*   Wg   = (u16*)(ws + off);   off += (size_t)9 * 128 * 128 * 2;
  float* shb  = (float*)(ws + off); off += 512;
  // total ~30 MB

  kv_proj<<<dim3(64, 8), 256, 0, stream>>>(x_skip, kv1_w, kv1_b, kv2_w, kv2_b,
                                           Knm, Vcm, K2t, V2t,
                                           conv_w, bn_g, bn_b, bn_m, bn_v, Wg, shb);
  attn_gram<<<dim3(80, 8), 512, 0, stream>>>(x_up, x_skip, (const u16*)Knm, Vcm,
                                             xcat, K2t, Mp);
  chan_reduce<<<128, 256, 0, stream>>>(Mp, M);
  chan_apply<<<dim3(64, 8), 256, 0, stream>>>(V2t, M, x_up, x_skip, xcat);
  conv_mfma<<<dim3(32, 8), 512, 0, stream>>>(xcat, Wg, shb, out);
}

// Round 3
// 330.153 us; speedup vs baseline: 1.9852x; 1.9852x over previous
//
#include <hip/hip_runtime.h>
#include <math.h>

#define HW 4096

typedef __attribute__((ext_vector_type(8))) short bh8;
typedef __attribute__((ext_vector_type(4))) float f32x4;
typedef __attribute__((ext_vector_type(2))) unsigned int u32x2;
typedef unsigned int u32;
typedef unsigned short u16;

__device__ __forceinline__ u16 f2bf(float f) {
  union { float f; u32 u; } v; v.f = f;
  u32 u = v.u;
  return (u16)((u + 0x7FFFu + ((u >> 16) & 1u)) >> 16);
}
__device__ __forceinline__ float bf2f(u16 h) {
  union { u32 u; float f; } v; v.u = ((u32)h) << 16;
  return v.f;
}
__device__ __forceinline__ u32 cvt_pk_bf16(float lo, float hi) {
  u32 r;
  asm("v_cvt_pk_bf16_f32 %0, %1, %2" : "=v"(r) : "v"(lo), "v"(hi));
  return r;
}
__device__ __forceinline__ float fexp2(float x) {
  float r;
  asm("v_exp_f32 %0, %1" : "=v"(r) : "v"(x));
  return r;
}

// ---------------------------------------------------------------------------
// kv projection (+ fused conv-weight convert prologue).  (unchanged from r1)
// ---------------------------------------------------------------------------
__global__ __launch_bounds__(256) void kv_proj(
    const float* __restrict__ xs,
    const float* __restrict__ w1, const float* __restrict__ b1,
    const float* __restrict__ w2, const float* __restrict__ b2,
    u32* __restrict__ Knm, u16* __restrict__ Vcm,
    u16* __restrict__ K2t, u16* __restrict__ V2t,
    const float* __restrict__ cw, const float* __restrict__ gamma,
    const float* __restrict__ beta, const float* __restrict__ mean,
    const float* __restrict__ var, u16* __restrict__ Wg,
    float* __restrict__ shb) {
  __shared__ float Ss[64][65];
  __shared__ float Ws[128 * 64];
  __shared__ u32 LtK[64][33];  // packed bf16x2 K rows, conflict-free pitch
  const int b = blockIdx.y, n0 = blockIdx.x * 64;
  const int t = threadIdx.x;
  const int lane_n = t & 63, jg = t >> 6;
  const int jbase = jg * 32;
  const float* xsb = xs + (size_t)b * 128 * HW;

  // ---- fused wcvt: conv_w (oc,ic,3,3) -> Wg[tap][oc][ic] bf16, BN folded ----
  {
    int gid = (blockIdx.y * 64 + blockIdx.x) * 256 + t;  // 0..131071
    for (int i = gid; i < 147456; i += 131072) {
      int tap = i >> 14, oc = (i >> 7) & 127, ic = i & 127;
      float sc = gamma[oc] * rsqrtf(var[oc] + 1e-5f);
      Wg[i] = f2bf(cw[((size_t)(oc * 128 + ic)) * 9 + tap] * sc);
    }
    if (gid < 128) {
      float sc = gamma[gid] * rsqrtf(var[gid] + 1e-5f);
      shb[gid] = beta[gid] - mean[gid] * sc;
    }
  }

  for (int br = 0; br < 2; ++br) {
    const float* W = br ? w2 : w1;
    const float* bias = br ? b2 : b1;
    const float* src = xsb + (br ? 64 * HW : 0);
    __syncthreads();
    for (int s = 0; s < 16; ++s) {
      int ch = s * 4 + jg;
      Ss[ch][lane_n] = src[(size_t)ch * HW + n0 + lane_n];
    }
    for (int i = t; i < 128 * 64; i += 256) Ws[i] = W[i];
    __syncthreads();

    float acc[32];
#pragma unroll
    for (int i = 0; i < 32; ++i) acc[i] = bias[jbase + i];
    for (int ch = 0; ch < 64; ++ch) {
      float s = Ss[ch][lane_n];
#pragma unroll
      for (int i = 0; i < 32; ++i) acc[i] = fmaf(Ws[(jbase + i) * 64 + ch], s, acc[i]);
    }

    if (br == 0) {
      if (jg < 2) {  // K channels jbase..jbase+31 -> pack to LDS
#pragma unroll
        for (int i2 = 0; i2 < 16; ++i2) {
          u32 p = (u32)f2bf(acc[2 * i2]) | ((u32)f2bf(acc[2 * i2 + 1]) << 16);
          LtK[lane_n][jg * 16 + i2] = p;
        }
      } else {  // V channels (jbase-64)..+31 -> bf16 ch-major global
#pragma unroll
        for (int i = 0; i < 32; ++i) {
          int ch = jbase - 64 + i;
          Vcm[((size_t)b * 64 + ch) * HW + n0 + lane_n] = f2bf(acc[i]);
        }
      }
      __syncthreads();
      // coalesced n-major K write: rows of 32 uints (64 bf16)
#pragma unroll
      for (int p = 0; p < 8; ++p) {
        int idx = p * 256 + t;
        int n = idx >> 5, cc = idx & 31;
        Knm[((size_t)b * HW + n0 + n) * 32 + cc] = LtK[n][cc];
      }
    } else {  // channel branch: bf16 ch-major K2t/V2t
      u16* Kt = K2t + (size_t)b * 64 * HW;
      u16* Vt = V2t + (size_t)b * 64 * HW;
#pragma unroll
      for (int i = 0; i < 32; ++i) {
        int j = jbase + i;
        u16* dst = (j < 64) ? (Kt + (size_t)j * HW) : (Vt + (size_t)(j - 64) * HW);
        dst[n0 + lane_n] = f2bf(acc[i]);
      }
    }
  }
}

// ---------------------------------------------------------------------------
// Fused dispatch, r9: back to the proven 256-thread/4-wave r1 structure but
// with q-tile 32 (was 64): per-block work halves, attn grid doubles to 128
// blocks/batch -> 1280 total blocks = 5/CU (register residency 4/CU = 16
// waves, vs r1's grid-limited 3). Per-wave state shrinks (O[4][2], qb[2][2])
// so VGPR stays well under 128 -- NO aggressive launch_bounds (R2 lesson:
// forcing VGPR=64 spilled 2 GB to scratch). Epilogue now single-round: all
// 4 waves' 64ch x 32q partials fit LDS at once. P stays in registers
// (cvt_pk_bf16 + permlane32/16_swap); exp2 without offset (scale cancels).
// grid (160, 8 b), block 256: x<128 attn, x>=128 gram (128-n chunks).
// ---------------------------------------------------------------------------
__device__ __forceinline__ void attn_step(
    const bh8* kf, const bh8* vf, const bh8 (&qb)[2][2], const bh8 ones,
    f32x4 (&O)[4][2], f32x4 (&Osum)[2]) {
  f32x4 S[2][2];
  __builtin_amdgcn_s_setprio(1);
#pragma unroll
  for (int mt = 0; mt < 2; ++mt)
#pragma unroll
    for (int nt = 0; nt < 2; ++nt) {
      f32x4 a = (f32x4)(0.f);
      a = __builtin_amdgcn_mfma_f32_16x16x32_bf16(kf[mt * 2 + 0], qb[nt][0], a, 0, 0, 0);
      a = __builtin_amdgcn_mfma_f32_16x16x32_bf16(kf[mt * 2 + 1], qb[nt][1], a, 0, 0, 0);
      S[mt][nt] = a;
    }
  __builtin_amdgcn_s_setprio(0);
#pragma unroll
  for (int nt = 0; nt < 2; ++nt) {
    // p = exp2(S)  (Q prescaled by log2e; global scale cancels at normalize)
    float e00 = fexp2(S[0][nt][0]), e01 = fexp2(S[0][nt][1]);
    float e02 = fexp2(S[0][nt][2]), e03 = fexp2(S[0][nt][3]);
    float e10 = fexp2(S[1][nt][0]), e11 = fexp2(S[1][nt][1]);
    float e12 = fexp2(S[1][nt][2]), e13 = fexp2(S[1][nt][3]);
    u32 A = cvt_pk_bf16(e00, e01);  // m0, keys quad*4+{0,1}
    u32 B = cvt_pk_bf16(e02, e03);  // m0, keys quad*4+{2,3}
    u32 C = cvt_pk_bf16(e10, e11);  // m1, keys 16+quad*4+{0,1}
    u32 D = cvt_pk_bf16(e12, e13);  // m1, keys 16+quad*4+{2,3}
    // redistribute (q=lane&15 preserved):
    // consumer quad qc needs m=qc>>1 from producer quads (qc&1)*2, (qc&1)*2+1
    u32x2 rac = __builtin_amdgcn_permlane32_swap(A, C, 0, 0);
    u32x2 rbd = __builtin_amdgcn_permlane32_swap(B, D, 0, 0);
    u32x2 r02 = __builtin_amdgcn_permlane16_swap(rac.x, rac.y, 0, 0);
    u32x2 r13 = __builtin_amdgcn_permlane16_swap(rbd.x, rbd.y, 0, 0);
    union { u32 u[4]; bh8 v; } pb;
    pb.u[0] = r02.x;  // keys quad*8+{0,1}
    pb.u[1] = r13.x;  // keys quad*8+{2,3}
    pb.u[2] = r02.y;  // keys quad*8+{4,5}
    pb.u[3] = r13.y;  // keys quad*8+{6,7}
    __builtin_amdgcn_s_setprio(1);
#pragma unroll
    for (int ct = 0; ct < 4; ++ct)
      O[ct][nt] = __builtin_amdgcn_mfma_f32_16x16x32_bf16(vf[ct], pb.v, O[ct][nt], 0, 0, 0);
    Osum[nt] = __builtin_amdgcn_mfma_f32_16x16x32_bf16(ones, pb.v, Osum[nt], 0, 0, 0);
    __builtin_amdgcn_s_setprio(0);
  }
}

#define LOADKV(KB, KF, VF)                                            \
  do {                                                                \
    const int n0_ = (KB) * 128;                                       \
    const u16* kr_ = Kb + (size_t)(n0_ + wb + lq) * 64 + quad * 8;    \
    KF[0] = *(const bh8*)(kr_);                                       \
    KF[1] = *(const bh8*)(kr_ + 32);                                  \
    KF[2] = *(const bh8*)(kr_ + 1024);                                \
    KF[3] = *(const bh8*)(kr_ + 1056);                                \
    const u16* vr_ = Vb + (size_t)lq * HW + n0_ + wb + quad * 8;      \
    VF[0] = *(const bh8*)(vr_);                                       \
    VF[1] = *(const bh8*)(vr_ + 16 * HW);                             \
    VF[2] = *(const bh8*)(vr_ + 32 * HW);                             \
    VF[3] = *(const bh8*)(vr_ + 48 * HW);                             \
  } while (0)

__global__ __launch_bounds__(256, 2) void attn_gram(
    const float* __restrict__ xu, const float* __restrict__ xs,
    const u16* __restrict__ Knm, const u16* __restrict__ Vcm,
    u16* __restrict__ xcat,
    const u16* __restrict__ K2t, float* __restrict__ Mp) {
  __shared__ __align__(16) u16 SMEM[18432];  // 36864 B
  const int b = blockIdx.y;
  const int t = threadIdx.x;

  if (blockIdx.x >= 128) {
    // ---------------- chan_gram path (r1 shape): 128 n per block ----------
    float* Us = (float*)SMEM;      // [64][65]
    float* Ksm = Us + 64 * 65;     // [64][65]
    const int n0 = (blockIdx.x - 128) * 128;
    const int c = t & 63, dg = t >> 6;
    const float* ub = xu + ((size_t)b * 128 + 64) * HW;
    const u16* kb2 = K2t + (size_t)b * 64 * HW;
    float acc[16];
#pragma unroll
    for (int i = 0; i < 16; ++i) acc[i] = 0.f;
    for (int s = 0; s < 2; ++s) {
      int nn = n0 + s * 64;
      __syncthreads();
      for (int r = 0; r < 16; ++r) {
        int row = r * 4 + dg;
        Us[row * 65 + c] = ub[(size_t)row * HW + nn + c];
        Ksm[row * 65 + c] = bf2f(kb2[(size_t)row * HW + nn + c]);
      }
      __syncthreads();
      for (int n = 0; n < 64; ++n) {
        float u = Us[c * 65 + n];
#pragma unroll
        for (int i = 0; i < 16; ++i)
          acc[i] = fmaf(Ksm[(dg * 16 + i) * 65 + n], u, acc[i]);
      }
    }
    float* dst = Mp + ((size_t)(blockIdx.x - 128) * 8 + b) * 4096 + c * 64 + dg * 16;
#pragma unroll
    for (int i = 0; i < 16; ++i) dst[i] = acc[i];
    return;
  }

  // ---------------- attention path: q-tile 32, 4 key-slicing waves --------
  const int q0 = blockIdx.x * 32;
  const int wq = t >> 6, lane = t & 63, lq = lane & 15, quad = lane >> 4;
  const int wb = wq * 32;  // wave's key-slice base within a 128-key tile
  const float* xub = xu + (size_t)b * 128 * HW;
  const float* xsb = xs + (size_t)b * 128 * HW;
  const u16* Kb = Knm + (size_t)b * HW * 64;
  const u16* Vb = Vcm + (size_t)b * 64 * HW;

  // Q B-fragments: 32 q x 64 ch per wave, prescaled by log2(e)
  bh8 qb[2][2];
#pragma unroll
  for (int nt = 0; nt < 2; ++nt)
#pragma unroll
    for (int s = 0; s < 2; ++s)
#pragma unroll
      for (int j = 0; j < 8; ++j) {
        int ch = s * 32 + quad * 8 + j;
        qb[nt][s][j] =
            (short)f2bf(xub[(size_t)ch * HW + q0 + nt * 16 + lq] * 1.44269504f);
      }
  bh8 ones;
#pragma unroll
  for (int j = 0; j < 8; ++j) ones[j] = (short)0x3F80;  // bf16 1.0

  f32x4 O[4][2];  // [ct: ch-tile][nt: q-tile], C: row=ch_local, col=q_local
#pragma unroll
  for (int ct = 0; ct < 4; ++ct)
#pragma unroll
    for (int nt = 0; nt < 2; ++nt) O[ct][nt] = (f32x4)(0.f);
  f32x4 Osum[2];  // all rows identical = sum over wave's keys, per q
#pragma unroll
  for (int nt = 0; nt < 2; ++nt) Osum[nt] = (f32x4)(0.f);

  bh8 kfa[4], vfa[4], kfb[4], vfb[4];
  LOADKV(0, kfa, vfa);
  for (int kb = 0; kb < 32; kb += 2) {
    LOADKV(kb + 1, kfb, vfb);
    attn_step(kfa, vfa, qb, ones, O, Osum);
    if (kb + 2 < 32) LOADKV(kb + 2, kfa, vfa);
    attn_step(kfb, vfb, qb, ones, O, Osum);
  }

  // ---- epilogue (single round): cross-wave reduce, normalize, store ----
  // Posc [4 waves][64 ch][32 q pitch 34] = 34816 B; Lred [4][32] = 512 B
  float* Posc = (float*)SMEM;
  float* Lred = (float*)(SMEM + 17408);  // u16 offset -> byte 34816
  if (quad == 0) {
#pragma unroll
    for (int nt = 0; nt < 2; ++nt) Lred[wq * 32 + nt * 16 + lq] = Osum[nt][0];
  }
#pragma unroll
  for (int ct = 0; ct < 4; ++ct)
#pragma unroll
    for (int nt = 0; nt < 2; ++nt)
#pragma unroll
      for (int r = 0; r < 4; ++r)
        Posc[(wq * 64 + ct * 16 + quad * 4 + r) * 34 + nt * 16 + lq] = O[ct][nt][r];
  __syncthreads();

  const int q = t & 31, cs = t >> 5;  // 32 q x 8 ch-groups of 8
  float li = Lred[q] + Lred[32 + q] + Lred[64 + q] + Lred[96 + q];
  float inv = 1.f / li;
  u16 h[8];
#pragma unroll
  for (int i = 0; i < 8; ++i) {
    int ch = cs * 8 + i;
    float s = 0.f;
#pragma unroll
    for (int w2 = 0; w2 < 4; ++w2) s += Posc[(w2 * 64 + ch) * 34 + q];
    size_t g = (size_t)ch * HW + q0 + q;
    h[i] = f2bf(s * inv + xub[g] + xsb[g]);
  }
  u32 pk[4];
#pragma unroll
  for (int j = 0; j < 4; ++j) pk[j] = (u32)h[2 * j] | ((u32)h[2 * j + 1] << 16);
  *(uint4*)(xcat + ((size_t)b * HW + q0 + q) * 128 + cs * 8) =
      make_uint4(pk[0], pk[1], pk[2], pk[3]);
}

// reduce 32 chunk-partials -> M. grid 128, block 256.
__global__ void chan_reduce(const float* __restrict__ Mp, float* __restrict__ M) {
  int idx = blockIdx.x * 256 + threadIdx.x;  // 32768 cells
  float s = 0.f;
  for (int ch = 0; ch < 32; ++ch) s += Mp[(size_t)ch * 32768 + idx];
  M[idx] = s;
}

// ---------------------------------------------------------------------------
// chan_apply with fused softmax (unchanged)
// ---------------------------------------------------------------------------
__global__ __launch_bounds__(256) void chan_apply(
    const u16* __restrict__ V2t, const float* __restrict__ M,
    const float* __restrict__ xu, const float* __restrict__ xs,
    u16* __restrict__ xcat) {
  __shared__ float Vsm[64][65];
  __shared__ float As[64][65];
  __shared__ float red1[4][64], red2[4][64];
  const int b = blockIdx.y, n0 = blockIdx.x * 64, t = threadIdx.x;
  const int lane = t & 63, dg = t >> 6;
  const u16* Vb = V2t + (size_t)b * 64 * HW;
  for (int s = 0; s < 16; ++s) {
    int c = s * 4 + dg;
    Vsm[lane][c] = bf2f(Vb[(size_t)c * HW + n0 + lane]);
  }
  for (int idx = t; idx < 4096; idx += 256) As[idx >> 6][idx & 63] = M[b * 4096 + idx];
  __syncthreads();
  // softmax over c per d=lane; this thread owns c in [dg*16, dg*16+16)
  float mx = -1e30f;
#pragma unroll
  for (int i = 0; i < 16; ++i) mx = fmaxf(mx, As[dg * 16 + i][lane]);
  red1[dg][lane] = mx;
  __syncthreads();
  mx = fmaxf(fmaxf(red1[0][lane], red1[1][lane]), fmaxf(red1[2][lane], red1[3][lane]));
  float se = 0.f;
#pragma unroll
  for (int i = 0; i < 16; ++i) {
    float e = __expf(As[dg * 16 + i][lane] - mx);
    As[dg * 16 + i][lane] = e;  // own cells only
    se += e;
  }
  red2[dg][lane] = se;
  __syncthreads();

  float acc[16];
#pragma unroll
  for (int i = 0; i < 16; ++i) acc[i] = 0.f;
  for (int c = 0; c < 64; ++c) {
    float v = Vsm[lane][c];
#pragma unroll
    for (int i = 0; i < 16; ++i) acc[i] = fmaf(v, As[c][dg * 16 + i], acc[i]);
  }
  const float* xub = xu + ((size_t)b * 128 + 64) * HW;
  const float* xsb = xs + ((size_t)b * 128 + 64) * HW;
  const int n = n0 + lane;
  u16 hv[16];
#pragma unroll
  for (int i = 0; i < 16; ++i) {
    int d = dg * 16 + i;
    float sm = red2[0][d] + red2[1][d] + red2[2][d] + red2[3][d];
    hv[i] = f2bf(acc[i] / sm + xub[(size_t)d * HW + n] + xsb[(size_t)d * HW + n]);
  }
  u32 pk[8];
#pragma unroll
  for (int j = 0; j < 8; ++j) pk[j] = (u32)hv[2 * j] | ((u32)hv[2 * j + 1] << 16);
  u16* ob = xcat + ((size_t)b * HW + n) * 128 + 64 + dg * 16;
  *(uint4*)(ob) = make_uint4(pk[0], pk[1], pk[2], pk[3]);
  *(uint4*)(ob + 8) = make_uint4(pk[4], pk[5], pk[6], pk[7]);
}

// ---------------------------------------------------------------------------
// Implicit-GEMM 3x3 conv via bf16 MFMA + fused BN(folded) + ReLU. (unchanged)
// ---------------------------------------------------------------------------
__global__ __launch_bounds__(512) void conv_mfma(
    const u16* __restrict__ X, const u16* __restrict__ Wg,
    const float* __restrict__ shb, float* __restrict__ out) {
  __shared__ __align__(16) u16 In[4 * 66 * 136];
  __shared__ __align__(16) u16 Wt[2][128 * 136];
  const int b = blockIdx.y, h0 = blockIdx.x * 2;
  const int t = threadIdx.x;
  const int wq = t >> 6, lane = t & 63, lq = lane & 15, quad = lane >> 4;
  const int nb = (wq & 1) * 64;       // oc-half base
  const int mb = (wq >> 1) * 2;       // m-tile pair base
  const u16* Xb = X + (size_t)b * HW * 128;

  // zero w-halo cells (iw = 0 and 65 for each ih)
  if (t < 128) {
    int ih = t >> 5, iwsel = (t >> 4) & 1, ck = t & 15;
    int iw = iwsel ? 65 : 0;
    *(uint4*)&In[(ih * 66 + iw) * 136 + ck * 8] = make_uint4(0, 0, 0, 0);
  }
  // stage input rows (zero h-halo out of range); 512 threads
  for (int ih = 0; ih < 4; ++ih) {
    int h = h0 - 1 + ih;
    bool ok = (h >= 0 && h < 64);
    const u16* src = Xb + (size_t)h * 64 * 128;
#pragma unroll
    for (int p = 0; p < 2; ++p) {
      int idx = p * 512 + t;
      int row = idx >> 4, ck = idx & 15;
      uint4 d = make_uint4(0, 0, 0, 0);
      if (ok) d = *(const uint4*)(src + (size_t)row * 128 + ck * 8);
      *(uint4*)&In[(ih * 66 + 1 + row) * 136 + ck * 8] = d;
    }
  }
  // stage tap-0 weights into buffer 0 (2048 uint4 over 512 threads = 4 passes)
  {
    const u16* src = Wg;
#pragma unroll
    for (int p = 0; p < 4; ++p) {
      int idx = p * 512 + t;
      int oc = idx >> 4, ck = idx & 15;
      uint4 d = *(const uint4*)(src + oc * 128 + ck * 8);
      *(uint4*)&Wt[0][oc * 136 + ck * 8] = d;
    }
  }
  __syncthreads();

  f32x4 acc[2][4];
#pragma unroll
  for (int mt = 0; mt < 2; ++mt)
#pragma unroll
    for (int nt = 0; nt < 4; ++nt) acc[mt][nt] = (f32x4)(0.f);

  for (int tap = 0; tap < 9; ++tap) {
    const int cur = tap & 1;
    if (tap < 8) {  // prefetch next tap into the other buffer
      const u16* src = Wg + (size_t)(tap + 1) * 128 * 128;
#pragma unroll
      for (int p = 0; p < 4; ++p) {
        int idx = p * 512 + t;
        int oc = idx >> 4, ck = idx & 15;
        uint4 d = *(const uint4*)(src + oc * 128 + ck * 8);
        *(uint4*)&Wt[cur ^ 1][oc * 136 + ck * 8] = d;
      }
    }
    const int dh = tap / 3, dw = tap - 3 * dh;
    const u16* Wc = &Wt[cur][0];
#pragma unroll
    for (int c = 0; c < 4; ++c) {
      bh8 bf[4];
#pragma unroll
      for (int nt = 0; nt < 4; ++nt)
        bf[nt] = *(const bh8*)&Wc[(nb + nt * 16 + lq) * 136 + c * 32 + quad * 8];
#pragma unroll
      for (int mt = 0; mt < 2; ++mt) {
        int s = (mb + mt) * 16 + lq;
        int ih = (s >> 6) + dh, iw = (s & 63) + dw;
        bh8 af = *(const bh8*)&In[(ih * 66 + iw) * 136 + c * 32 + quad * 8];
#pragma unroll
        for (int nt = 0; nt < 4; ++nt)
          acc[mt][nt] = __builtin_amdgcn_mfma_f32_16x16x32_bf16(af, bf[nt], acc[mt][nt], 0, 0, 0);
      }
    }
    __syncthreads();
  }

  // epilogue: +bias, ReLU, dense float4 stores
  float shv[4];
#pragma unroll
  for (int nt = 0; nt < 4; ++nt) shv[nt] = shb[nb + nt * 16 + lq];
#pragma unroll
  for (int mt = 0; mt < 2; ++mt) {
    int mtile = mb + mt;
    int h = h0 + (mtile >> 2);
    int w0 = ((mtile & 3) * 16) + quad * 4;
#pragma unroll
    for (int nt = 0; nt < 4; ++nt) {
      int oc = nb + nt * 16 + lq;
      float4 v;
      v.x = fmaxf(acc[mt][nt][0] + shv[nt], 0.f);
      v.y = fmaxf(acc[mt][nt][1] + shv[nt], 0.f);
      v.z = fmaxf(acc[mt][nt][2] + shv[nt], 0.f);
      v.w = fmaxf(acc[mt][nt][3] + shv[nt], 0.f);
      *(float4*)&out[((size_t)b * 128 + oc) * HW + h * 64 + w0] = v;
    }
  }
}

// ---------------------------------------------------------------------------
extern "C" void kernel_launch(void* const* d_in, const int* in_sizes, int n_in,
                              void* d_out, int out_size, void* d_ws, size_t ws_size,
                              hipStream_t stream) {
  const float* x_up   = (const float*)d_in[0];
  const float* x_skip = (const float*)d_in[1];
  const float* kv1_w  = (const float*)d_in[2];
  const float* kv1_b  = (const float*)d_in[3];
  const float* kv2_w  = (const float*)d_in[4];
  const float* kv2_b  = (const float*)d_in[5];
  const float* conv_w = (const float*)d_in[6];
  const float* bn_g   = (const float*)d_in[7];
  const float* bn_b   = (const float*)d_in[8];
  const float* bn_m   = (const float*)d_in[9];
  const float* bn_v   = (const float*)d_in[10];
  float* out = (float*)d_out;

  char* ws = (char*)d_ws;
  const size_t XCATB_B = (size_t)8 * HW * 128 * 2;  // 8.39 MB bf16 n-major
  const size_t KV16_B  = (size_t)8 * 64 * HW * 2;   // 4.19 MB
  size_t off = 0;
  u16*   xcat = (u16*)(ws + off);   off += XCATB_B;
  u16*   K2t  = (u16*)(ws + off);   off += KV16_B;
  u16*   V2t  = (u16*)(ws + off);   off += KV16_B;
  u32*   Knm  = (u32*)(ws + off);   off += KV16_B;
  u16*   Vcm  = (u16*)(ws + off);   off += KV16_B;
  float* Mp   = (float*)(ws + off); off += (size_t)32 * 8 * 4096 * 4;
  float* M    = (float*)(ws + off); off += (size_t)8 * 4096 * 4;
  u16*   Wg   = (u16*)(ws + off);   off += (size_t)9 * 128 * 128 * 2;
  float* shb  = (float*)(ws + off); off += 512;
  // total ~30 MB

  kv_proj<<<dim3(64, 8), 256, 0, stream>>>(x_skip, kv1_w, kv1_b, kv2_w, kv2_b,
                                           Knm, Vcm, K2t, V2t,
                                           conv_w, bn_g, bn_b, bn_m, bn_v, Wg, shb);
  attn_gram<<<dim3(160, 8), 256, 0, stream>>>(x_up, x_skip, (const u16*)Knm, Vcm,
                                              xcat, K2t, Mp);
  chan_reduce<<<128, 256, 0, stream>>>(Mp, M);
  chan_apply<<<dim3(64, 8), 256, 0, stream>>>(V2t, M, x_up, x_skip, xcat);
  conv_mfma<<<dim3(32, 8), 512, 0, stream>>>(xcat, Wg, shb, out);
}

// Round 4
// 268.358 us; speedup vs baseline: 2.4424x; 1.2303x over previous
//
#include <hip/hip_runtime.h>
#include <math.h>

#define HW 4096

typedef __attribute__((ext_vector_type(8))) short bh8;
typedef __attribute__((ext_vector_type(4))) float f32x4;
typedef __attribute__((ext_vector_type(2))) unsigned int u32x2;
typedef unsigned int u32;
typedef unsigned short u16;

__device__ __forceinline__ u16 f2bf(float f) {
  union { float f; u32 u; } v; v.f = f;
  u32 u = v.u;
  return (u16)((u + 0x7FFFu + ((u >> 16) & 1u)) >> 16);
}
__device__ __forceinline__ float bf2f(u16 h) {
  union { u32 u; float f; } v; v.u = ((u32)h) << 16;
  return v.f;
}
__device__ __forceinline__ u32 cvt_pk_bf16(float lo, float hi) {
  u32 r;
  asm("v_cvt_pk_bf16_f32 %0, %1, %2" : "=v"(r) : "v"(lo), "v"(hi));
  return r;
}
__device__ __forceinline__ float fexp2(float x) {
  float r;
  asm("v_exp_f32 %0, %1" : "=v"(r) : "v"(x));
  return r;
}

// ---------------------------------------------------------------------------
// kv projection (+ fused conv-weight convert prologue).  (unchanged)
// ---------------------------------------------------------------------------
__global__ __launch_bounds__(256) void kv_proj(
    const float* __restrict__ xs,
    const float* __restrict__ w1, const float* __restrict__ b1,
    const float* __restrict__ w2, const float* __restrict__ b2,
    u32* __restrict__ Knm, u16* __restrict__ Vcm,
    u16* __restrict__ K2t, u16* __restrict__ V2t,
    const float* __restrict__ cw, const float* __restrict__ gamma,
    const float* __restrict__ beta, const float* __restrict__ mean,
    const float* __restrict__ var, u16* __restrict__ Wg,
    float* __restrict__ shb) {
  __shared__ float Ss[64][65];
  __shared__ float Ws[128 * 64];
  __shared__ u32 LtK[64][33];  // packed bf16x2 K rows, conflict-free pitch
  const int b = blockIdx.y, n0 = blockIdx.x * 64;
  const int t = threadIdx.x;
  const int lane_n = t & 63, jg = t >> 6;
  const int jbase = jg * 32;
  const float* xsb = xs + (size_t)b * 128 * HW;

  // ---- fused wcvt: conv_w (oc,ic,3,3) -> Wg[tap][oc][ic] bf16, BN folded ----
  {
    int gid = (blockIdx.y * 64 + blockIdx.x) * 256 + t;  // 0..131071
    for (int i = gid; i < 147456; i += 131072) {
      int tap = i >> 14, oc = (i >> 7) & 127, ic = i & 127;
      float sc = gamma[oc] * rsqrtf(var[oc] + 1e-5f);
      Wg[i] = f2bf(cw[((size_t)(oc * 128 + ic)) * 9 + tap] * sc);
    }
    if (gid < 128) {
      float sc = gamma[gid] * rsqrtf(var[gid] + 1e-5f);
      shb[gid] = beta[gid] - mean[gid] * sc;
    }
  }

  for (int br = 0; br < 2; ++br) {
    const float* W = br ? w2 : w1;
    const float* bias = br ? b2 : b1;
    const float* src = xsb + (br ? 64 * HW : 0);
    __syncthreads();
    for (int s = 0; s < 16; ++s) {
      int ch = s * 4 + jg;
      Ss[ch][lane_n] = src[(size_t)ch * HW + n0 + lane_n];
    }
    for (int i = t; i < 128 * 64; i += 256) Ws[i] = W[i];
    __syncthreads();

    float acc[32];
#pragma unroll
    for (int i = 0; i < 32; ++i) acc[i] = bias[jbase + i];
    for (int ch = 0; ch < 64; ++ch) {
      float s = Ss[ch][lane_n];
#pragma unroll
      for (int i = 0; i < 32; ++i) acc[i] = fmaf(Ws[(jbase + i) * 64 + ch], s, acc[i]);
    }

    if (br == 0) {
      if (jg < 2) {  // K channels jbase..jbase+31 -> pack to LDS
#pragma unroll
        for (int i2 = 0; i2 < 16; ++i2) {
          u32 p = (u32)f2bf(acc[2 * i2]) | ((u32)f2bf(acc[2 * i2 + 1]) << 16);
          LtK[lane_n][jg * 16 + i2] = p;
        }
      } else {  // V channels (jbase-64)..+31 -> bf16 ch-major global
#pragma unroll
        for (int i = 0; i < 32; ++i) {
          int ch = jbase - 64 + i;
          Vcm[((size_t)b * 64 + ch) * HW + n0 + lane_n] = f2bf(acc[i]);
        }
      }
      __syncthreads();
      // coalesced n-major K write: rows of 32 uints (64 bf16)
#pragma unroll
      for (int p = 0; p < 8; ++p) {
        int idx = p * 256 + t;
        int n = idx >> 5, cc = idx & 31;
        Knm[((size_t)b * HW + n0 + n) * 32 + cc] = LtK[n][cc];
      }
    } else {  // channel branch: bf16 ch-major K2t/V2t
      u16* Kt = K2t + (size_t)b * 64 * HW;
      u16* Vt = V2t + (size_t)b * 64 * HW;
#pragma unroll
      for (int i = 0; i < 32; ++i) {
        int j = jbase + i;
        u16* dst = (j < 64) ? (Kt + (size_t)j * HW) : (Vt + (size_t)(j - 64) * HW);
        dst[n0 + lane_n] = f2bf(acc[i]);
      }
    }
  }
}

// ---------------------------------------------------------------------------
// Fused dispatch, r10: r1 attention core (q-tile 64, 4 key-sliced waves,
// VGPR~112, conflict-free pitch-68 epilogue) + 2-way KEY SPLIT for occupancy:
// block (q0,ks) covers keys [ks*2048, ks*2048+2048). Per-block load:compute
// ratio identical to r1 (R3 lesson), but grid = 1280 blocks = 5/CU so the
// VGPR/LDS-permitted 4 blocks/CU actually fills (r1 was grid-capped at 3).
// Softmax is exp2(S) with no running max -> partials are LINEAR: block writes
// unnormalized O-sums (f32) + l-sums; combine fused into the chan dispatch.
// XCD batch-affinity: flattened grid, b = bid&7 -> each XCD's L2 holds one
// batch's K/V (1 MB of 4 MB).
// grid 1280 (xblk<128: attn q0=(xblk>>1)*64, ks=xblk&1; else gram), block 256
// ---------------------------------------------------------------------------
__device__ __forceinline__ void attn_step(
    const bh8* kf, const bh8* vf, const bh8 (&qb)[4][2], const bh8 ones,
    f32x4 (&O)[4][4], f32x4 (&Osum)[4]) {
  f32x4 S[2][4];
  __builtin_amdgcn_s_setprio(1);
#pragma unroll
  for (int mt = 0; mt < 2; ++mt)
#pragma unroll
    for (int nt = 0; nt < 4; ++nt) {
      f32x4 a = (f32x4)(0.f);
      a = __builtin_amdgcn_mfma_f32_16x16x32_bf16(kf[mt * 2 + 0], qb[nt][0], a, 0, 0, 0);
      a = __builtin_amdgcn_mfma_f32_16x16x32_bf16(kf[mt * 2 + 1], qb[nt][1], a, 0, 0, 0);
      S[mt][nt] = a;
    }
  __builtin_amdgcn_s_setprio(0);
#pragma unroll
  for (int nt = 0; nt < 4; ++nt) {
    // p = exp2(S)  (Q prescaled by log2e; global scale cancels at normalize)
    float e00 = fexp2(S[0][nt][0]), e01 = fexp2(S[0][nt][1]);
    float e02 = fexp2(S[0][nt][2]), e03 = fexp2(S[0][nt][3]);
    float e10 = fexp2(S[1][nt][0]), e11 = fexp2(S[1][nt][1]);
    float e12 = fexp2(S[1][nt][2]), e13 = fexp2(S[1][nt][3]);
    u32 A = cvt_pk_bf16(e00, e01);  // m0, keys quad*4+{0,1}
    u32 B = cvt_pk_bf16(e02, e03);  // m0, keys quad*4+{2,3}
    u32 C = cvt_pk_bf16(e10, e11);  // m1, keys 16+quad*4+{0,1}
    u32 D = cvt_pk_bf16(e12, e13);  // m1, keys 16+quad*4+{2,3}
    // redistribute (q=lane&15 preserved):
    // consumer quad qc needs m=qc>>1 from producer quads (qc&1)*2, (qc&1)*2+1
    u32x2 rac = __builtin_amdgcn_permlane32_swap(A, C, 0, 0);
    u32x2 rbd = __builtin_amdgcn_permlane32_swap(B, D, 0, 0);
    u32x2 r02 = __builtin_amdgcn_permlane16_swap(rac.x, rac.y, 0, 0);
    u32x2 r13 = __builtin_amdgcn_permlane16_swap(rbd.x, rbd.y, 0, 0);
    union { u32 u[4]; bh8 v; } pb;
    pb.u[0] = r02.x;  // keys quad*8+{0,1}
    pb.u[1] = r13.x;  // keys quad*8+{2,3}
    pb.u[2] = r02.y;  // keys quad*8+{4,5}
    pb.u[3] = r13.y;  // keys quad*8+{6,7}
    __builtin_amdgcn_s_setprio(1);
#pragma unroll
    for (int ct = 0; ct < 4; ++ct)
      O[ct][nt] = __builtin_amdgcn_mfma_f32_16x16x32_bf16(vf[ct], pb.v, O[ct][nt], 0, 0, 0);
    Osum[nt] = __builtin_amdgcn_mfma_f32_16x16x32_bf16(ones, pb.v, Osum[nt], 0, 0, 0);
    __builtin_amdgcn_s_setprio(0);
  }
}

#define LOADKV(KB, KF, VF)                                            \
  do {                                                                \
    const int n0_ = (KB) * 128;                                       \
    const u16* kr_ = Kb + (size_t)(n0_ + wb + lq) * 64 + quad * 8;    \
    KF[0] = *(const bh8*)(kr_);                                       \
    KF[1] = *(const bh8*)(kr_ + 32);                                  \
    KF[2] = *(const bh8*)(kr_ + 1024);                                \
    KF[3] = *(const bh8*)(kr_ + 1056);                                \
    const u16* vr_ = Vb + (size_t)lq * HW + n0_ + wb + quad * 8;      \
    VF[0] = *(const bh8*)(vr_);                                       \
    VF[1] = *(const bh8*)(vr_ + 16 * HW);                             \
    VF[2] = *(const bh8*)(vr_ + 32 * HW);                             \
    VF[3] = *(const bh8*)(vr_ + 48 * HW);                             \
  } while (0)

__global__ __launch_bounds__(256, 2) void attn_gram(
    const float* __restrict__ xu, const float* __restrict__ xs,
    const u16* __restrict__ Knm, const u16* __restrict__ Vcm,
    const u16* __restrict__ K2t, float* __restrict__ Mp,
    float* __restrict__ Opart, float* __restrict__ Lpart) {
  __shared__ __align__(16) u16 SMEM[18432];  // 36864 B
  const int bid = blockIdx.x;
  const int b = bid & 7;        // XCD batch affinity (bid%8 -> XCD)
  const int xblk = bid >> 3;    // 0..159
  const int t = threadIdx.x;

  if (xblk >= 128) {
    // ---------------- chan_gram path: 128 n per block ----------------
    float* Us = (float*)SMEM;      // [64][65]
    float* Ksm = Us + 64 * 65;     // [64][65]
    const int chunk = xblk - 128;
    const int n0 = chunk * 128;
    const int c = t & 63, dg = t >> 6;
    const float* ub = xu + ((size_t)b * 128 + 64) * HW;
    const u16* kb2 = K2t + (size_t)b * 64 * HW;
    float acc[16];
#pragma unroll
    for (int i = 0; i < 16; ++i) acc[i] = 0.f;
    for (int s = 0; s < 2; ++s) {
      int nn = n0 + s * 64;
      __syncthreads();
      for (int r = 0; r < 16; ++r) {
        int row = r * 4 + dg;
        Us[row * 65 + c] = ub[(size_t)row * HW + nn + c];
        Ksm[row * 65 + c] = bf2f(kb2[(size_t)row * HW + nn + c]);
      }
      __syncthreads();
      for (int n = 0; n < 64; ++n) {
        float u = Us[c * 65 + n];
#pragma unroll
        for (int i = 0; i < 16; ++i)
          acc[i] = fmaf(Ksm[(dg * 16 + i) * 65 + n], u, acc[i]);
      }
    }
    float* dst = Mp + ((size_t)chunk * 8 + b) * 4096 + c * 64 + dg * 16;
#pragma unroll
    for (int i = 0; i < 16; ++i) dst[i] = acc[i];
    return;
  }

  // ---------------- attention path: q-tile 64, key-half ks ----------------
  const int q0 = (xblk >> 1) * 64;
  const int ks = xblk & 1;
  const int kbase = ks * 16;  // 16 x 128-key tiles per half
  const int wq = t >> 6, lane = t & 63, lq = lane & 15, quad = lane >> 4;
  const int wb = wq * 32;  // wave's key-slice base within a 128-key tile
  const float* xub = xu + (size_t)b * 128 * HW;
  const u16* Kb = Knm + (size_t)b * HW * 64;
  const u16* Vb = Vcm + (size_t)b * 64 * HW;

  // Q B-fragments: all 64 q x 64 ch per wave, prescaled by log2(e)
  bh8 qb[4][2];
#pragma unroll
  for (int nt = 0; nt < 4; ++nt)
#pragma unroll
    for (int s = 0; s < 2; ++s)
#pragma unroll
      for (int j = 0; j < 8; ++j) {
        int ch = s * 32 + quad * 8 + j;
        qb[nt][s][j] =
            (short)f2bf(xub[(size_t)ch * HW + q0 + nt * 16 + lq] * 1.44269504f);
      }
  bh8 ones;
#pragma unroll
  for (int j = 0; j < 8; ++j) ones[j] = (short)0x3F80;  // bf16 1.0

  f32x4 O[4][4];  // [ct: ch-tile][nt: q-tile], C: row=ch_local, col=q_local
#pragma unroll
  for (int ct = 0; ct < 4; ++ct)
#pragma unroll
    for (int nt = 0; nt < 4; ++nt) O[ct][nt] = (f32x4)(0.f);
  f32x4 Osum[4];  // all rows identical = sum over wave's keys, per q
#pragma unroll
  for (int nt = 0; nt < 4; ++nt) Osum[nt] = (f32x4)(0.f);

  bh8 kfa[4], vfa[4], kfb[4], vfb[4];
  LOADKV(kbase, kfa, vfa);
  for (int kb = 0; kb < 16; kb += 2) {
    LOADKV(kbase + kb + 1, kfb, vfb);
    attn_step(kfa, vfa, qb, ones, O, Osum);
    if (kb + 2 < 16) LOADKV(kbase + kb + 2, kfa, vfa);
    attn_step(kfb, vfb, qb, ones, O, Osum);
  }

  // ---- epilogue: cross-wave reduce -> UNNORMALIZED f32 partials ----
  float* Posc = (float*)SMEM;            // [4 waves][32 ch][68 q] = 34816 B
  float* Lred = (float*)(SMEM + 17408);  // [4 waves][4 nt][16 lq] = 1024 B
  if (quad == 0) {
#pragma unroll
    for (int nt = 0; nt < 4; ++nt) Lred[(wq * 4 + nt) * 16 + lq] = Osum[nt][0];
  }

  const int q = t & 63, cg = t >> 6;
  float* Ob = Opart + (((size_t)b * 2 + ks) * HW + q0 + q) * 64;
#pragma unroll
  for (int rh = 0; rh < 2; ++rh) {
    if (rh) __syncthreads();  // previous half's readers done
#pragma unroll
    for (int c2 = 0; c2 < 2; ++c2)
#pragma unroll
      for (int nt = 0; nt < 4; ++nt)
#pragma unroll
        for (int r = 0; r < 4; ++r)
          Posc[(wq * 32 + c2 * 16 + quad * 4 + r) * 68 + nt * 16 + lq] =
              O[rh * 2 + c2][nt][r];
    __syncthreads();
    if (rh == 0 && cg == 0) {
      float li = 0.f;
#pragma unroll
      for (int w2 = 0; w2 < 4; ++w2) li += Lred[w2 * 64 + q];
      Lpart[((size_t)b * 2 + ks) * HW + q0 + q] = li;
    }
    float s4[8];
#pragma unroll
    for (int i = 0; i < 8; ++i) {
      int chl = cg * 8 + i;
      float s = 0.f;
#pragma unroll
      for (int w2 = 0; w2 < 4; ++w2) s += Posc[(w2 * 32 + chl) * 68 + q];
      s4[i] = s;
    }
    float4 v0 = make_float4(s4[0], s4[1], s4[2], s4[3]);
    float4 v1 = make_float4(s4[4], s4[5], s4[6], s4[7]);
    *(float4*)(Ob + rh * 32 + cg * 8) = v0;
    *(float4*)(Ob + rh * 32 + cg * 8 + 4) = v1;
  }
}

// reduce 32 chunk-partials -> M. grid 128, block 256.
__global__ void chan_reduce(const float* __restrict__ Mp, float* __restrict__ M) {
  int idx = blockIdx.x * 256 + threadIdx.x;  // 32768 cells
  float s = 0.f;
  for (int ch = 0; ch < 32; ++ch) s += Mp[(size_t)ch * 32768 + idx];
  M[idx] = s;
}

// ---------------------------------------------------------------------------
// Fused chan dispatch: x<64 -> chan_apply (softmax + V2*A + shortcut2, ch
// 64..127); x>=64 -> attention combine ((P0+P1)/(l0+l1) + shortcut1, ch
// 0..63). Both write disjoint xcat halves. Flattened grid w/ b = bid&7.
// grid 1024, block 256
// ---------------------------------------------------------------------------
__global__ __launch_bounds__(256) void chan_fused(
    const u16* __restrict__ V2t, const float* __restrict__ M,
    const float* __restrict__ xu, const float* __restrict__ xs,
    u16* __restrict__ xcat,
    const float* __restrict__ Opart, const float* __restrict__ Lpart) {
  const int bid = blockIdx.x;
  const int b = bid & 7;
  const int x = bid >> 3;  // 0..127
  const int t = threadIdx.x;

  if (x >= 64) {
    // ---------------- attention combine path ----------------
    const int q0c = (x - 64) * 64;
    const int q = t & 63, cg = t >> 6;  // cg: 16 ch each
    const int qq = q0c + q;
    const float* O0 = Opart + ((size_t)b * 2 * HW + qq) * 64 + cg * 16;
    const float* O1 = O0 + (size_t)HW * 64;
    float l = Lpart[(size_t)b * 2 * HW + qq] + Lpart[((size_t)b * 2 + 1) * HW + qq];
    float inv = 1.f / l;
    const float* xub = xu + (size_t)b * 128 * HW;
    const float* xsb = xs + (size_t)b * 128 * HW;
    u16 h[16];
#pragma unroll
    for (int i = 0; i < 16; ++i) {
      int ch = cg * 16 + i;
      size_t g = (size_t)ch * HW + qq;
      h[i] = f2bf((O0[i] + O1[i]) * inv + xub[g] + xsb[g]);
    }
    u32 pk[8];
#pragma unroll
    for (int j = 0; j < 8; ++j) pk[j] = (u32)h[2 * j] | ((u32)h[2 * j + 1] << 16);
    u16* ob = xcat + ((size_t)b * HW + qq) * 128 + cg * 16;
    *(uint4*)(ob) = make_uint4(pk[0], pk[1], pk[2], pk[3]);
    *(uint4*)(ob + 8) = make_uint4(pk[4], pk[5], pk[6], pk[7]);
    return;
  }

  // ---------------- chan_apply path ----------------
  __shared__ float Vsm[64][65];
  __shared__ float As[64][65];
  __shared__ float red1[4][64], red2[4][64];
  const int n0 = x * 64;
  const int lane = t & 63, dg = t >> 6;
  const u16* Vb = V2t + (size_t)b * 64 * HW;
  for (int s = 0; s < 16; ++s) {
    int c = s * 4 + dg;
    Vsm[lane][c] = bf2f(Vb[(size_t)c * HW + n0 + lane]);
  }
  for (int idx = t; idx < 4096; idx += 256) As[idx >> 6][idx & 63] = M[b * 4096 + idx];
  __syncthreads();
  // softmax over c per d=lane; this thread owns c in [dg*16, dg*16+16)
  float mx = -1e30f;
#pragma unroll
  for (int i = 0; i < 16; ++i) mx = fmaxf(mx, As[dg * 16 + i][lane]);
  red1[dg][lane] = mx;
  __syncthreads();
  mx = fmaxf(fmaxf(red1[0][lane], red1[1][lane]), fmaxf(red1[2][lane], red1[3][lane]));
  float se = 0.f;
#pragma unroll
  for (int i = 0; i < 16; ++i) {
    float e = __expf(As[dg * 16 + i][lane] - mx);
    As[dg * 16 + i][lane] = e;  // own cells only
    se += e;
  }
  red2[dg][lane] = se;
  __syncthreads();

  float acc[16];
#pragma unroll
  for (int i = 0; i < 16; ++i) acc[i] = 0.f;
  for (int c = 0; c < 64; ++c) {
    float v = Vsm[lane][c];
#pragma unroll
    for (int i = 0; i < 16; ++i) acc[i] = fmaf(v, As[c][dg * 16 + i], acc[i]);
  }
  const float* xub = xu + ((size_t)b * 128 + 64) * HW;
  const float* xsb = xs + ((size_t)b * 128 + 64) * HW;
  const int n = n0 + lane;
  u16 hv[16];
#pragma unroll
  for (int i = 0; i < 16; ++i) {
    int d = dg * 16 + i;
    float sm = red2[0][d] + red2[1][d] + red2[2][d] + red2[3][d];
    hv[i] = f2bf(acc[i] / sm + xub[(size_t)d * HW + n] + xsb[(size_t)d * HW + n]);
  }
  u32 pk[8];
#pragma unroll
  for (int j = 0; j < 8; ++j) pk[j] = (u32)hv[2 * j] | ((u32)hv[2 * j + 1] << 16);
  u16* ob = xcat + ((size_t)b * HW + n) * 128 + 64 + dg * 16;
  *(uint4*)(ob) = make_uint4(pk[0], pk[1], pk[2], pk[3]);
  *(uint4*)(ob + 8) = make_uint4(pk[4], pk[5], pk[6], pk[7]);
}

// ---------------------------------------------------------------------------
// Implicit-GEMM 3x3 conv via bf16 MFMA + fused BN(folded) + ReLU. (unchanged)
// ---------------------------------------------------------------------------
__global__ __launch_bounds__(512) void conv_mfma(
    const u16* __restrict__ X, const u16* __restrict__ Wg,
    const float* __restrict__ shb, float* __restrict__ out) {
  __shared__ __align__(16) u16 In[4 * 66 * 136];
  __shared__ __align__(16) u16 Wt[2][128 * 136];
  const int b = blockIdx.y, h0 = blockIdx.x * 2;
  const int t = threadIdx.x;
  const int wq = t >> 6, lane = t & 63, lq = lane & 15, quad = lane >> 4;
  const int nb = (wq & 1) * 64;       // oc-half base
  const int mb = (wq >> 1) * 2;       // m-tile pair base
  const u16* Xb = X + (size_t)b * HW * 128;

  // zero w-halo cells (iw = 0 and 65 for each ih)
  if (t < 128) {
    int ih = t >> 5, iwsel = (t >> 4) & 1, ck = t & 15;
    int iw = iwsel ? 65 : 0;
    *(uint4*)&In[(ih * 66 + iw) * 136 + ck * 8] = make_uint4(0, 0, 0, 0);
  }
  // stage input rows (zero h-halo out of range); 512 threads
  for (int ih = 0; ih < 4; ++ih) {
    int h = h0 - 1 + ih;
    bool ok = (h >= 0 && h < 64);
    const u16* src = Xb + (size_t)h * 64 * 128;
#pragma unroll
    for (int p = 0; p < 2; ++p) {
      int idx = p * 512 + t;
      int row = idx >> 4, ck = idx & 15;
      uint4 d = make_uint4(0, 0, 0, 0);
      if (ok) d = *(const uint4*)(src + (size_t)row * 128 + ck * 8);
      *(uint4*)&In[(ih * 66 + 1 + row) * 136 + ck * 8] = d;
    }
  }
  // stage tap-0 weights into buffer 0 (2048 uint4 over 512 threads = 4 passes)
  {
    const u16* src = Wg;
#pragma unroll
    for (int p = 0; p < 4; ++p) {
      int idx = p * 512 + t;
      int oc = idx >> 4, ck = idx & 15;
      uint4 d = *(const uint4*)(src + oc * 128 + ck * 8);
      *(uint4*)&Wt[0][oc * 136 + ck * 8] = d;
    }
  }
  __syncthreads();

  f32x4 acc[2][4];
#pragma unroll
  for (int mt = 0; mt < 2; ++mt)
#pragma unroll
    for (int nt = 0; nt < 4; ++nt) acc[mt][nt] = (f32x4)(0.f);

  for (int tap = 0; tap < 9; ++tap) {
    const int cur = tap & 1;
    if (tap < 8) {  // prefetch next tap into the other buffer
      const u16* src = Wg + (size_t)(tap + 1) * 128 * 128;
#pragma unroll
      for (int p = 0; p < 4; ++p) {
        int idx = p * 512 + t;
        int oc = idx >> 4, ck = idx & 15;
        uint4 d = *(const uint4*)(src + oc * 128 + ck * 8);
        *(uint4*)&Wt[cur ^ 1][oc * 136 + ck * 8] = d;
      }
    }
    const int dh = tap / 3, dw = tap - 3 * dh;
    const u16* Wc = &Wt[cur][0];
#pragma unroll
    for (int c = 0; c < 4; ++c) {
      bh8 bf[4];
#pragma unroll
      for (int nt = 0; nt < 4; ++nt)
        bf[nt] = *(const bh8*)&Wc[(nb + nt * 16 + lq) * 136 + c * 32 + quad * 8];
#pragma unroll
      for (int mt = 0; mt < 2; ++mt) {
        int s = (mb + mt) * 16 + lq;
        int ih = (s >> 6) + dh, iw = (s & 63) + dw;
        bh8 af = *(const bh8*)&In[(ih * 66 + iw) * 136 + c * 32 + quad * 8];
#pragma unroll
        for (int nt = 0; nt < 4; ++nt)
          acc[mt][nt] = __builtin_amdgcn_mfma_f32_16x16x32_bf16(af, bf[nt], acc[mt][nt], 0, 0, 0);
      }
    }
    __syncthreads();
  }

  // epilogue: +bias, ReLU, dense float4 stores
  float shv[4];
#pragma unroll
  for (int nt = 0; nt < 4; ++nt) shv[nt] = shb[nb + nt * 16 + lq];
#pragma unroll
  for (int mt = 0; mt < 2; ++mt) {
    int mtile = mb + mt;
    int h = h0 + (mtile >> 2);
    int w0 = ((mtile & 3) * 16) + quad * 4;
#pragma unroll
    for (int nt = 0; nt < 4; ++nt) {
      int oc = nb + nt * 16 + lq;
      float4 v;
      v.x = fmaxf(acc[mt][nt][0] + shv[nt], 0.f);
      v.y = fmaxf(acc[mt][nt][1] + shv[nt], 0.f);
      v.z = fmaxf(acc[mt][nt][2] + shv[nt], 0.f);
      v.w = fmaxf(acc[mt][nt][3] + shv[nt], 0.f);
      *(float4*)&out[((size_t)b * 128 + oc) * HW + h * 64 + w0] = v;
    }
  }
}

// ---------------------------------------------------------------------------
extern "C" void kernel_launch(void* const* d_in, const int* in_sizes, int n_in,
                              void* d_out, int out_size, void* d_ws, size_t ws_size,
                              hipStream_t stream) {
  const float* x_up   = (const float*)d_in[0];
  const float* x_skip = (const float*)d_in[1];
  const float* kv1_w  = (const float*)d_in[2];
  const float* kv1_b  = (const float*)d_in[3];
  const float* kv2_w  = (const float*)d_in[4];
  const float* kv2_b  = (const float*)d_in[5];
  const float* conv_w = (const float*)d_in[6];
  const float* bn_g   = (const float*)d_in[7];
  const float* bn_b   = (const float*)d_in[8];
  const float* bn_m   = (const float*)d_in[9];
  const float* bn_v   = (const float*)d_in[10];
  float* out = (float*)d_out;

  char* ws = (char*)d_ws;
  const size_t XCATB_B = (size_t)8 * HW * 128 * 2;  // 8.39 MB bf16 n-major
  const size_t KV16_B  = (size_t)8 * 64 * HW * 2;   // 4.19 MB
  size_t off = 0;
  u16*   xcat = (u16*)(ws + off);   off += XCATB_B;
  u16*   K2t  = (u16*)(ws + off);   off += KV16_B;
  u16*   V2t  = (u16*)(ws + off);   off += KV16_B;
  u32*   Knm  = (u32*)(ws + off);   off += KV16_B;
  u16*   Vcm  = (u16*)(ws + off);   off += KV16_B;
  float* Mp   = (float*)(ws + off); off += (size_t)32 * 8 * 4096 * 4;
  float* M    = (float*)(ws + off); off += (size_t)8 * 4096 * 4;
  u16*   Wg   = (u16*)(ws + off);   off += (size_t)9 * 128 * 128 * 2;
  float* shb  = (float*)(ws + off); off += 512;
  float* Opart = (float*)(ws + off); off += (size_t)8 * 2 * HW * 64 * 4;  // 16.8 MB
  float* Lpart = (float*)(ws + off); off += (size_t)8 * 2 * HW * 4;       // 256 KB
  // total ~47 MB

  kv_proj<<<dim3(64, 8), 256, 0, stream>>>(x_skip, kv1_w, kv1_b, kv2_w, kv2_b,
                                           Knm, Vcm, K2t, V2t,
                                           conv_w, bn_g, bn_b, bn_m, bn_v, Wg, shb);
  attn_gram<<<1280, 256, 0, stream>>>(x_up, x_skip, (const u16*)Knm, Vcm,
                                      K2t, Mp, Opart, Lpart);
  chan_reduce<<<128, 256, 0, stream>>>(Mp, M);
  chan_fused<<<1024, 256, 0, stream>>>(V2t, M, x_up, x_skip, xcat, Opart, Lpart);
  conv_mfma<<<dim3(32, 8), 512, 0, stream>>>(xcat, Wg, shb, out);
}

// Round 5
// 211.842 us; speedup vs baseline: 3.0940x; 1.2668x over previous
//
#include <hip/hip_runtime.h>
#include <math.h>

#define HW 4096

typedef __attribute__((ext_vector_type(8))) short bh8;
typedef __attribute__((ext_vector_type(4))) float f32x4;
typedef __attribute__((ext_vector_type(2))) unsigned int u32x2;
typedef unsigned int u32;
typedef unsigned short u16;

__device__ __forceinline__ u16 f2bf(float f) {
  union { float f; u32 u; } v; v.f = f;
  u32 u = v.u;
  return (u16)((u + 0x7FFFu + ((u >> 16) & 1u)) >> 16);
}
__device__ __forceinline__ float bf2f(u16 h) {
  union { u32 u; float f; } v; v.u = ((u32)h) << 16;
  return v.f;
}
__device__ __forceinline__ float ubits2f(u32 u) {
  union { u32 u; float f; } v; v.u = u;
  return v.f;
}
__device__ __forceinline__ u32 cvt_pk_bf16(float lo, float hi) {
  u32 r;
  asm("v_cvt_pk_bf16_f32 %0, %1, %2" : "=v"(r) : "v"(lo), "v"(hi));
  return r;
}
__device__ __forceinline__ float fexp2(float x) {
  float r;
  asm("v_exp_f32 %0, %1" : "=v"(r) : "v"(x));
  return r;
}

// ---------------------------------------------------------------------------
// kv projection, r11: bf16 MFMA GEMM with split-precision residual
// (Whi*Xhi + Whi*Xlo + Wlo*Xhi => f32-accurate kv, same storage rounding as
// the old VALU-f32 path). Replaces the VALU GEMM whose inner loop issued one
// ds_read_b32 per FMA. W fragments load straight to registers (coalesced
// float4); x stages via LDS transposed [n][72] (2-way bank alias = free) so
// B-fragments are contiguous ds_read_b128. Output layouts unchanged.
// Fused conv-weight convert prologue unchanged. grid (64,8), block 256.
// ---------------------------------------------------------------------------
__global__ __launch_bounds__(256) void kv_proj(
    const float* __restrict__ xs,
    const float* __restrict__ w1, const float* __restrict__ b1,
    const float* __restrict__ w2, const float* __restrict__ b2,
    u32* __restrict__ Knm, u16* __restrict__ Vcm,
    u16* __restrict__ K2t, u16* __restrict__ V2t,
    const float* __restrict__ cw, const float* __restrict__ gamma,
    const float* __restrict__ beta, const float* __restrict__ mean,
    const float* __restrict__ var, u16* __restrict__ Wg,
    float* __restrict__ shb) {
  __shared__ __align__(16) u16 XsH[64][72];
  __shared__ __align__(16) u16 XsL[64][72];
  __shared__ u32 LtK[64][33];
  const int b = blockIdx.y, n0 = blockIdx.x * 64;
  const int t = threadIdx.x;
  const int wq = t >> 6, lane = t & 63, lq = lane & 15, quad = lane >> 4;
  const float* xsb = xs + (size_t)b * 128 * HW;

  // ---- fused wcvt: conv_w (oc,ic,3,3) -> Wg[tap][oc][ic] bf16, BN folded ----
  {
    int gid = (blockIdx.y * 64 + blockIdx.x) * 256 + t;  // 0..131071
    for (int i = gid; i < 147456; i += 131072) {
      int tap = i >> 14, oc = (i >> 7) & 127, ic = i & 127;
      float sc = gamma[oc] * rsqrtf(var[oc] + 1e-5f);
      Wg[i] = f2bf(cw[((size_t)(oc * 128 + ic)) * 9 + tap] * sc);
    }
    if (gid < 128) {
      float sc = gamma[gid] * rsqrtf(var[gid] + 1e-5f);
      shb[gid] = beta[gid] - mean[gid] * sc;
    }
  }

  for (int br = 0; br < 2; ++br) {
    const float* W = br ? w2 : w1;
    const float* bias = br ? b2 : b1;
    const float* src = xsb + (br ? 64 * HW : 0);

    // ---- W fragments -> registers, split hi/lo bf16 ----
    bh8 wh[2][2], wl[2][2];
#pragma unroll
    for (int jt = 0; jt < 2; ++jt)
#pragma unroll
      for (int s = 0; s < 2; ++s) {
        const float* wr = W + (size_t)(wq * 32 + jt * 16 + lq) * 64 + s * 32 + quad * 8;
        float4 a0 = *(const float4*)wr;
        float4 a1 = *(const float4*)(wr + 4);
        float f[8] = {a0.x, a0.y, a0.z, a0.w, a1.x, a1.y, a1.z, a1.w};
        union { u32 u[4]; bh8 v; } H, L;
#pragma unroll
        for (int p = 0; p < 4; ++p) {
          u32 hp = cvt_pk_bf16(f[2 * p], f[2 * p + 1]);
          float h0 = ubits2f(hp << 16);
          float h1 = ubits2f(hp & 0xFFFF0000u);
          H.u[p] = hp;
          L.u[p] = cvt_pk_bf16(f[2 * p] - h0, f[2 * p + 1] - h1);
        }
        wh[jt][s] = H.v;
        wl[jt][s] = L.v;
      }

    if (br) __syncthreads();  // prior branch's LDS readers/writers done
    // ---- stage x tile transposed to LDS as hi/lo bf16 ----
    {
      const int n = t & 63, cg = t >> 6;
#pragma unroll
      for (int s8 = 0; s8 < 8; ++s8) {
        int ch0 = s8 * 8 + cg * 2;
        float f0 = src[(size_t)ch0 * HW + n0 + n];
        float f1 = src[(size_t)(ch0 + 1) * HW + n0 + n];
        u32 hp = cvt_pk_bf16(f0, f1);
        float h0 = ubits2f(hp << 16);
        float h1 = ubits2f(hp & 0xFFFF0000u);
        u32 lp = cvt_pk_bf16(f0 - h0, f1 - h1);
        *(u32*)&XsH[n][ch0] = hp;
        *(u32*)&XsL[n][ch0] = lp;
      }
    }
    __syncthreads();

    // ---- MFMA: out[j][n] = W[j][:] . x[:][n], 8 C-tiles per wave ----
    f32x4 acc[2][4];
#pragma unroll
    for (int nt = 0; nt < 4; ++nt) {
      const int xr = nt * 16 + lq;
      bh8 xh0 = *(const bh8*)&XsH[xr][quad * 8];
      bh8 xh1 = *(const bh8*)&XsH[xr][32 + quad * 8];
      bh8 xl0 = *(const bh8*)&XsL[xr][quad * 8];
      bh8 xl1 = *(const bh8*)&XsL[xr][32 + quad * 8];
#pragma unroll
      for (int jt = 0; jt < 2; ++jt) {
        f32x4 a = (f32x4)(0.f);
        a = __builtin_amdgcn_mfma_f32_16x16x32_bf16(wh[jt][0], xh0, a, 0, 0, 0);
        a = __builtin_amdgcn_mfma_f32_16x16x32_bf16(wh[jt][1], xh1, a, 0, 0, 0);
        a = __builtin_amdgcn_mfma_f32_16x16x32_bf16(wh[jt][0], xl0, a, 0, 0, 0);
        a = __builtin_amdgcn_mfma_f32_16x16x32_bf16(wh[jt][1], xl1, a, 0, 0, 0);
        a = __builtin_amdgcn_mfma_f32_16x16x32_bf16(wl[jt][0], xh0, a, 0, 0, 0);
        a = __builtin_amdgcn_mfma_f32_16x16x32_bf16(wl[jt][1], xh1, a, 0, 0, 0);
        acc[jt][nt] = a;
      }
    }

    // ---- epilogue ----
    if (br == 0) {
      if (wq < 2) {  // j 0..63 -> K1: pack pairs into LtK
#pragma unroll
        for (int jt = 0; jt < 2; ++jt) {
          float4 bv = *(const float4*)&bias[wq * 32 + jt * 16 + quad * 4];
#pragma unroll
          for (int nt = 0; nt < 4; ++nt) {
            f32x4 a = acc[jt][nt];
            LtK[nt * 16 + lq][wq * 16 + jt * 8 + quad * 2] =
                cvt_pk_bf16(a[0] + bv.x, a[1] + bv.y);
            LtK[nt * 16 + lq][wq * 16 + jt * 8 + quad * 2 + 1] =
                cvt_pk_bf16(a[2] + bv.z, a[3] + bv.w);
          }
        }
      } else {  // j 64..127 -> V1 ch-major bf16
#pragma unroll
        for (int jt = 0; jt < 2; ++jt) {
          float4 bv = *(const float4*)&bias[wq * 32 + jt * 16 + quad * 4];
          float bvv[4] = {bv.x, bv.y, bv.z, bv.w};
#pragma unroll
          for (int nt = 0; nt < 4; ++nt)
#pragma unroll
            for (int r = 0; r < 4; ++r) {
              int ch = (wq - 2) * 32 + jt * 16 + quad * 4 + r;
              Vcm[((size_t)b * 64 + ch) * HW + n0 + nt * 16 + lq] =
                  f2bf(acc[jt][nt][r] + bvv[r]);
            }
        }
      }
      __syncthreads();
      // coalesced n-major K write: rows of 32 uints (64 bf16)
#pragma unroll
      for (int p = 0; p < 8; ++p) {
        int idx = p * 256 + t;
        int n = idx >> 5, cc = idx & 31;
        Knm[((size_t)b * HW + n0 + n) * 32 + cc] = LtK[n][cc];
      }
    } else {  // branch 2: K2t / V2t ch-major bf16
      u16* base = (wq < 2) ? (K2t + (size_t)b * 64 * HW) : (V2t + (size_t)b * 64 * HW);
      const int chb = (wq & 1) * 32;
#pragma unroll
      for (int jt = 0; jt < 2; ++jt) {
        float4 bv = *(const float4*)&bias[wq * 32 + jt * 16 + quad * 4];
        float bvv[4] = {bv.x, bv.y, bv.z, bv.w};
#pragma unroll
        for (int nt = 0; nt < 4; ++nt)
#pragma unroll
          for (int r = 0; r < 4; ++r) {
            int ch = chb + jt * 16 + quad * 4 + r;
            base[(size_t)ch * HW + n0 + nt * 16 + lq] =
                f2bf(acc[jt][nt][r] + bvv[r]);
          }
      }
    }
  }
}

// ---------------------------------------------------------------------------
// Fused dispatch (exact r1 structure, the measured-best): blocks x<64 run
// MFMA flash attention (q-tile 64, 4 key-sliced waves, in-register P via
// cvt_pk + permlane, Osum via ones-MFMA, exp2 no offset); x>=64 chan_gram.
// grid (96, 8 b), block 256
// ---------------------------------------------------------------------------
__device__ __forceinline__ void attn_step(
    const bh8* kf, const bh8* vf, const bh8 (&qb)[4][2], const bh8 ones,
    f32x4 (&O)[4][4], f32x4 (&Osum)[4]) {
  f32x4 S[2][4];
  __builtin_amdgcn_s_setprio(1);
#pragma unroll
  for (int mt = 0; mt < 2; ++mt)
#pragma unroll
    for (int nt = 0; nt < 4; ++nt) {
      f32x4 a = (f32x4)(0.f);
      a = __builtin_amdgcn_mfma_f32_16x16x32_bf16(kf[mt * 2 + 0], qb[nt][0], a, 0, 0, 0);
      a = __builtin_amdgcn_mfma_f32_16x16x32_bf16(kf[mt * 2 + 1], qb[nt][1], a, 0, 0, 0);
      S[mt][nt] = a;
    }
  __builtin_amdgcn_s_setprio(0);
#pragma unroll
  for (int nt = 0; nt < 4; ++nt) {
    float e00 = fexp2(S[0][nt][0]), e01 = fexp2(S[0][nt][1]);
    float e02 = fexp2(S[0][nt][2]), e03 = fexp2(S[0][nt][3]);
    float e10 = fexp2(S[1][nt][0]), e11 = fexp2(S[1][nt][1]);
    float e12 = fexp2(S[1][nt][2]), e13 = fexp2(S[1][nt][3]);
    u32 A = cvt_pk_bf16(e00, e01);
    u32 B = cvt_pk_bf16(e02, e03);
    u32 C = cvt_pk_bf16(e10, e11);
    u32 D = cvt_pk_bf16(e12, e13);
    u32x2 rac = __builtin_amdgcn_permlane32_swap(A, C, 0, 0);
    u32x2 rbd = __builtin_amdgcn_permlane32_swap(B, D, 0, 0);
    u32x2 r02 = __builtin_amdgcn_permlane16_swap(rac.x, rac.y, 0, 0);
    u32x2 r13 = __builtin_amdgcn_permlane16_swap(rbd.x, rbd.y, 0, 0);
    union { u32 u[4]; bh8 v; } pb;
    pb.u[0] = r02.x;
    pb.u[1] = r13.x;
    pb.u[2] = r02.y;
    pb.u[3] = r13.y;
    __builtin_amdgcn_s_setprio(1);
#pragma unroll
    for (int ct = 0; ct < 4; ++ct)
      O[ct][nt] = __builtin_amdgcn_mfma_f32_16x16x32_bf16(vf[ct], pb.v, O[ct][nt], 0, 0, 0);
    Osum[nt] = __builtin_amdgcn_mfma_f32_16x16x32_bf16(ones, pb.v, Osum[nt], 0, 0, 0);
    __builtin_amdgcn_s_setprio(0);
  }
}

#define LOADKV(KB, KF, VF)                                            \
  do {                                                                \
    const int n0_ = (KB) * 128;                                       \
    const u16* kr_ = Kb + (size_t)(n0_ + wb + lq) * 64 + quad * 8;    \
    KF[0] = *(const bh8*)(kr_);                                       \
    KF[1] = *(const bh8*)(kr_ + 32);                                  \
    KF[2] = *(const bh8*)(kr_ + 1024);                                \
    KF[3] = *(const bh8*)(kr_ + 1056);                                \
    const u16* vr_ = Vb + (size_t)lq * HW + n0_ + wb + quad * 8;      \
    VF[0] = *(const bh8*)(vr_);                                       \
    VF[1] = *(const bh8*)(vr_ + 16 * HW);                             \
    VF[2] = *(const bh8*)(vr_ + 32 * HW);                             \
    VF[3] = *(const bh8*)(vr_ + 48 * HW);                             \
  } while (0)

__global__ __launch_bounds__(256, 2) void attn_gram(
    const float* __restrict__ xu, const float* __restrict__ xs,
    const u16* __restrict__ Knm, const u16* __restrict__ Vcm,
    u16* __restrict__ xcat,
    const u16* __restrict__ K2t, float* __restrict__ Mp) {
  __shared__ __align__(16) u16 SMEM[18432];  // 36864 B
  const int b = blockIdx.y;
  const int t = threadIdx.x;

  if (blockIdx.x >= 64) {
    // ---------------- chan_gram path ----------------
    float* Us = (float*)SMEM;      // [64][65]
    float* Ksm = Us + 64 * 65;     // [64][65]
    const int n0 = (blockIdx.x - 64) * 128;
    const int c = t & 63, dg = t >> 6;
    const float* ub = xu + ((size_t)b * 128 + 64) * HW;
    const u16* kb2 = K2t + (size_t)b * 64 * HW;
    float acc[16];
#pragma unroll
    for (int i = 0; i < 16; ++i) acc[i] = 0.f;
    for (int s = 0; s < 2; ++s) {
      int nn = n0 + s * 64;
      __syncthreads();
      for (int r = 0; r < 16; ++r) {
        int row = r * 4 + dg;
        Us[row * 65 + c] = ub[(size_t)row * HW + nn + c];
        Ksm[row * 65 + c] = bf2f(kb2[(size_t)row * HW + nn + c]);
      }
      __syncthreads();
      for (int n = 0; n < 64; ++n) {
        float u = Us[c * 65 + n];
#pragma unroll
        for (int i = 0; i < 16; ++i)
          acc[i] = fmaf(Ksm[(dg * 16 + i) * 65 + n], u, acc[i]);
      }
    }
    float* dst = Mp + ((size_t)(blockIdx.x - 64) * 8 + b) * 4096 + c * 64 + dg * 16;
#pragma unroll
    for (int i = 0; i < 16; ++i) dst[i] = acc[i];
    return;
  }

  // ---------------- attention path ----------------
  const int q0 = blockIdx.x * 64;
  const int wq = t >> 6, lane = t & 63, lq = lane & 15, quad = lane >> 4;
  const int wb = wq * 32;
  const float* xub = xu + (size_t)b * 128 * HW;
  const float* xsb = xs + (size_t)b * 128 * HW;
  const u16* Kb = Knm + (size_t)b * HW * 64;
  const u16* Vb = Vcm + (size_t)b * 64 * HW;

  bh8 qb[4][2];
#pragma unroll
  for (int nt = 0; nt < 4; ++nt)
#pragma unroll
    for (int s = 0; s < 2; ++s)
#pragma unroll
      for (int j = 0; j < 8; ++j) {
        int ch = s * 32 + quad * 8 + j;
        qb[nt][s][j] =
            (short)f2bf(xub[(size_t)ch * HW + q0 + nt * 16 + lq] * 1.44269504f);
      }
  bh8 ones;
#pragma unroll
  for (int j = 0; j < 8; ++j) ones[j] = (short)0x3F80;

  f32x4 O[4][4];
#pragma unroll
  for (int ct = 0; ct < 4; ++ct)
#pragma unroll
    for (int nt = 0; nt < 4; ++nt) O[ct][nt] = (f32x4)(0.f);
  f32x4 Osum[4];
#pragma unroll
  for (int nt = 0; nt < 4; ++nt) Osum[nt] = (f32x4)(0.f);

  bh8 kfa[4], vfa[4], kfb[4], vfb[4];
  LOADKV(0, kfa, vfa);
  for (int kb = 0; kb < 32; kb += 2) {
    LOADKV(kb + 1, kfb, vfb);
    attn_step(kfa, vfa, qb, ones, O, Osum);
    if (kb + 2 < 32) LOADKV(kb + 2, kfa, vfa);
    attn_step(kfb, vfb, qb, ones, O, Osum);
  }

  // ---- epilogue: cross-wave reduce, normalize, shortcut, bf16 store ----
  float* Posc = (float*)SMEM;            // [4 waves][32 ch][68 q] = 34816 B
  float* Lred = (float*)(SMEM + 17408);  // 1024 B
  if (quad == 0) {
#pragma unroll
    for (int nt = 0; nt < 4; ++nt) Lred[(wq * 4 + nt) * 16 + lq] = Osum[nt][0];
  }

  const int q = t & 63, cg = t >> 6;
#pragma unroll
  for (int rh = 0; rh < 2; ++rh) {
    if (rh) __syncthreads();
#pragma unroll
    for (int c2 = 0; c2 < 2; ++c2)
#pragma unroll
      for (int nt = 0; nt < 4; ++nt)
#pragma unroll
        for (int r = 0; r < 4; ++r)
          Posc[(wq * 32 + c2 * 16 + quad * 4 + r) * 68 + nt * 16 + lq] =
              O[rh * 2 + c2][nt][r];
    __syncthreads();
    float li = 0.f;
#pragma unroll
    for (int w2 = 0; w2 < 4; ++w2) li += Lred[w2 * 64 + q];
    float inv = 1.f / li;
    u16 h[8];
#pragma unroll
    for (int i = 0; i < 8; ++i) {
      int chl = cg * 8 + i;
      float s = 0.f;
#pragma unroll
      for (int w2 = 0; w2 < 4; ++w2) s += Posc[(w2 * 32 + chl) * 68 + q];
      int ch = rh * 32 + chl;
      size_t g = (size_t)ch * HW + q0 + q;
      h[i] = f2bf(s * inv + xub[g] + xsb[g]);
    }
    u32 pk[4];
#pragma unroll
    for (int j = 0; j < 4; ++j) pk[j] = (u32)h[2 * j] | ((u32)h[2 * j + 1] << 16);
    u16* ob = xcat + ((size_t)b * HW + q0 + q) * 128 + rh * 32 + cg * 8;
    *(uint4*)ob = make_uint4(pk[0], pk[1], pk[2], pk[3]);
  }
}

// reduce 32 chunk-partials -> M. grid 128, block 256.
__global__ void chan_reduce(const float* __restrict__ Mp, float* __restrict__ M) {
  int idx = blockIdx.x * 256 + threadIdx.x;  // 32768 cells
  float s = 0.f;
  for (int ch = 0; ch < 32; ++ch) s += Mp[(size_t)ch * 32768 + idx];
  M[idx] = s;
}

// ---------------------------------------------------------------------------
// chan_apply with fused softmax (unchanged r1)
// ---------------------------------------------------------------------------
__global__ __launch_bounds__(256) void chan_apply(
    const u16* __restrict__ V2t, const float* __restrict__ M,
    const float* __restrict__ xu, const float* __restrict__ xs,
    u16* __restrict__ xcat) {
  __shared__ float Vsm[64][65];
  __shared__ float As[64][65];
  __shared__ float red1[4][64], red2[4][64];
  const int b = blockIdx.y, n0 = blockIdx.x * 64, t = threadIdx.x;
  const int lane = t & 63, dg = t >> 6;
  const u16* Vb = V2t + (size_t)b * 64 * HW;
  for (int s = 0; s < 16; ++s) {
    int c = s * 4 + dg;
    Vsm[lane][c] = bf2f(Vb[(size_t)c * HW + n0 + lane]);
  }
  for (int idx = t; idx < 4096; idx += 256) As[idx >> 6][idx & 63] = M[b * 4096 + idx];
  __syncthreads();
  float mx = -1e30f;
#pragma unroll
  for (int i = 0; i < 16; ++i) mx = fmaxf(mx, As[dg * 16 + i][lane]);
  red1[dg][lane] = mx;
  __syncthreads();
  mx = fmaxf(fmaxf(red1[0][lane], red1[1][lane]), fmaxf(red1[2][lane], red1[3][lane]));
  float se = 0.f;
#pragma unroll
  for (int i = 0; i < 16; ++i) {
    float e = __expf(As[dg * 16 + i][lane] - mx);
    As[dg * 16 + i][lane] = e;
    se += e;
  }
  red2[dg][lane] = se;
  __syncthreads();

  float acc[16];
#pragma unroll
  for (int i = 0; i < 16; ++i) acc[i] = 0.f;
  for (int c = 0; c < 64; ++c) {
    float v = Vsm[lane][c];
#pragma unroll
    for (int i = 0; i < 16; ++i) acc[i] = fmaf(v, As[c][dg * 16 + i], acc[i]);
  }
  const float* xub = xu + ((size_t)b * 128 + 64) * HW;
  const float* xsb = xs + ((size_t)b * 128 + 64) * HW;
  const int n = n0 + lane;
  u16 hv[16];
#pragma unroll
  for (int i = 0; i < 16; ++i) {
    int d = dg * 16 + i;
    float sm = red2[0][d] + red2[1][d] + red2[2][d] + red2[3][d];
    hv[i] = f2bf(acc[i] / sm + xub[(size_t)d * HW + n] + xsb[(size_t)d * HW + n]);
  }
  u32 pk[8];
#pragma unroll
  for (int j = 0; j < 8; ++j) pk[j] = (u32)hv[2 * j] | ((u32)hv[2 * j + 1] << 16);
  u16* ob = xcat + ((size_t)b * HW + n) * 128 + 64 + dg * 16;
  *(uint4*)(ob) = make_uint4(pk[0], pk[1], pk[2], pk[3]);
  *(uint4*)(ob + 8) = make_uint4(pk[4], pk[5], pk[6], pk[7]);
}

// ---------------------------------------------------------------------------
// Implicit-GEMM 3x3 conv via bf16 MFMA + fused BN(folded) + ReLU. (unchanged)
// ---------------------------------------------------------------------------
__global__ __launch_bounds__(512) void conv_mfma(
    const u16* __restrict__ X, const u16* __restrict__ Wg,
    const float* __restrict__ shb, float* __restrict__ out) {
  __shared__ __align__(16) u16 In[4 * 66 * 136];
  __shared__ __align__(16) u16 Wt[2][128 * 136];
  const int b = blockIdx.y, h0 = blockIdx.x * 2;
  const int t = threadIdx.x;
  const int wq = t >> 6, lane = t & 63, lq = lane & 15, quad = lane >> 4;
  const int nb = (wq & 1) * 64;
  const int mb = (wq >> 1) * 2;
  const u16* Xb = X + (size_t)b * HW * 128;

  if (t < 128) {
    int ih = t >> 5, iwsel = (t >> 4) & 1, ck = t & 15;
    int iw = iwsel ? 65 : 0;
    *(uint4*)&In[(ih * 66 + iw) * 136 + ck * 8] = make_uint4(0, 0, 0, 0);
  }
  for (int ih = 0; ih < 4; ++ih) {
    int h = h0 - 1 + ih;
    bool ok = (h >= 0 && h < 64);
    const u16* src = Xb + (size_t)h * 64 * 128;
#pragma unroll
    for (int p = 0; p < 2; ++p) {
      int idx = p * 512 + t;
      int row = idx >> 4, ck = idx & 15;
      uint4 d = make_uint4(0, 0, 0, 0);
      if (ok) d = *(const uint4*)(src + (size_t)row * 128 + ck * 8);
      *(uint4*)&In[(ih * 66 + 1 + row) * 136 + ck * 8] = d;
    }
  }
  {
    const u16* src = Wg;
#pragma unroll
    for (int p = 0; p < 4; ++p) {
      int idx = p * 512 + t;
      int oc = idx >> 4, ck = idx & 15;
      uint4 d = *(const uint4*)(src + oc * 128 + ck * 8);
      *(uint4*)&Wt[0][oc * 136 + ck * 8] = d;
    }
  }
  __syncthreads();

  f32x4 acc[2][4];
#pragma unroll
  for (int mt = 0; mt < 2; ++mt)
#pragma unroll
    for (int nt = 0; nt < 4; ++nt) acc[mt][nt] = (f32x4)(0.f);

  for (int tap = 0; tap < 9; ++tap) {
    const int cur = tap & 1;
    if (tap < 8) {
      const u16* src = Wg + (size_t)(tap + 1) * 128 * 128;
#pragma unroll
      for (int p = 0; p < 4; ++p) {
        int idx = p * 512 + t;
        int oc = idx >> 4, ck = idx & 15;
        uint4 d = *(const uint4*)(src + oc * 128 + ck * 8);
        *(uint4*)&Wt[cur ^ 1][oc * 136 + ck * 8] = d;
      }
    }
    const int dh = tap / 3, dw = tap - 3 * dh;
    const u16* Wc = &Wt[cur][0];
#pragma unroll
    for (int c = 0; c < 4; ++c) {
      bh8 bf[4];
#pragma unroll
      for (int nt = 0; nt < 4; ++nt)
        bf[nt] = *(const bh8*)&Wc[(nb + nt * 16 + lq) * 136 + c * 32 + quad * 8];
#pragma unroll
      for (int mt = 0; mt < 2; ++mt) {
        int s = (mb + mt) * 16 + lq;
        int ih = (s >> 6) + dh, iw = (s & 63) + dw;
        bh8 af = *(const bh8*)&In[(ih * 66 + iw) * 136 + c * 32 + quad * 8];
#pragma unroll
        for (int nt = 0; nt < 4; ++nt)
          acc[mt][nt] = __builtin_amdgcn_mfma_f32_16x16x32_bf16(af, bf[nt], acc[mt][nt], 0, 0, 0);
      }
    }
    __syncthreads();
  }

  float shv[4];
#pragma unroll
  for (int nt = 0; nt < 4; ++nt) shv[nt] = shb[nb + nt * 16 + lq];
#pragma unroll
  for (int mt = 0; mt < 2; ++mt) {
    int mtile = mb + mt;
    int h = h0 + (mtile >> 2);
    int w0 = ((mtile & 3) * 16) + quad * 4;
#pragma unroll
    for (int nt = 0; nt < 4; ++nt) {
      int oc = nb + nt * 16 + lq;
      float4 v;
      v.x = fmaxf(acc[mt][nt][0] + shv[nt], 0.f);
      v.y = fmaxf(acc[mt][nt][1] + shv[nt], 0.f);
      v.z = fmaxf(acc[mt][nt][2] + shv[nt], 0.f);
      v.w = fmaxf(acc[mt][nt][3] + shv[nt], 0.f);
      *(float4*)&out[((size_t)b * 128 + oc) * HW + h * 64 + w0] = v;
    }
  }
}

// ---------------------------------------------------------------------------
extern "C" void kernel_launch(void* const* d_in, const int* in_sizes, int n_in,
                              void* d_out, int out_size, void* d_ws, size_t ws_size,
                              hipStream_t stream) {
  const float* x_up   = (const float*)d_in[0];
  const float* x_skip = (const float*)d_in[1];
  const float* kv1_w  = (const float*)d_in[2];
  const float* kv1_b  = (const float*)d_in[3];
  const float* kv2_w  = (const float*)d_in[4];
  const float* kv2_b  = (const float*)d_in[5];
  const float* conv_w = (const float*)d_in[6];
  const float* bn_g   = (const float*)d_in[7];
  const float* bn_b   = (const float*)d_in[8];
  const float* bn_m   = (const float*)d_in[9];
  const float* bn_v   = (const float*)d_in[10];
  float* out = (float*)d_out;

  char* ws = (char*)d_ws;
  const size_t XCATB_B = (size_t)8 * HW * 128 * 2;  // 8.39 MB bf16 n-major
  const size_t KV16_B  = (size_t)8 * 64 * HW * 2;   // 4.19 MB
  size_t off = 0;
  u16*   xcat = (u16*)(ws + off);   off += XCATB_B;
  u16*   K2t  = (u16*)(ws + off);   off += KV16_B;
  u16*   V2t  = (u16*)(ws + off);   off += KV16_B;
  u32*   Knm  = (u32*)(ws + off);   off += KV16_B;
  u16*   Vcm  = (u16*)(ws + off);   off += KV16_B;
  float* Mp   = (float*)(ws + off); off += (size_t)32 * 8 * 4096 * 4;
  float* M    = (float*)(ws + off); off += (size_t)8 * 4096 * 4;
  u16*   Wg   = (u16*)(ws + off);   off += (size_t)9 * 128 * 128 * 2;
  float* shb  = (float*)(ws + off); off += 512;
  // total ~30 MB

  kv_proj<<<dim3(64, 8), 256, 0, stream>>>(x_skip, kv1_w, kv1_b, kv2_w, kv2_b,
                                           Knm, Vcm, K2t, V2t,
                                           conv_w, bn_g, bn_b, bn_m, bn_v, Wg, shb);
  attn_gram<<<dim3(96, 8), 256, 0, stream>>>(x_up, x_skip, (const u16*)Knm, Vcm,
                                             xcat, K2t, Mp);
  chan_reduce<<<128, 256, 0, stream>>>(Mp, M);
  chan_apply<<<dim3(64, 8), 256, 0, stream>>>(V2t, M, x_up, x_skip, xcat);
  conv_mfma<<<dim3(32, 8), 512, 0, stream>>>(xcat, Wg, shb, out);
}